// Round 9
// baseline (354.117 us; speedup 1.0000x reference)
//
#include <hip/hip_runtime.h>
#include <hip/hip_cooperative_groups.h>
#include <cstdint>

namespace cg = cooperative_groups;

#define T_TOK 4096
#define KDIM 2048
#define NE 64
#define NP 2
#define EE 32
#define CAP 160
#define NKC 8
#define KCHUNK 256
#define BLKR 128
#define COMB_ELEMS 41943040ull /* 8192 * 5120 */
#define OUT_ELEMS 83886081ull  /* 1 + 2*COMB */
#define SMALLF 65544           /* floats of small scratch (incl. 2 ctrs) */
#define PARTF 2097152ull
#define TOT4 20971520          /* float4s covering OUT_ELEMS-1 */
#define NFB 4096
#define UNITS 16384u           /* fill units of 1280 float4 */
#define RESERVE_B 1024u
#define PB_F 81788928          /* pathB: part at out+PB_F (f4 20447232) */

// ---------------- wave-granular atomic fill drain ----------------------------
__device__ __forceinline__ void fill_units(float* __restrict__ out,
                                           unsigned int* __restrict__ ctr,
                                           unsigned int ubase, unsigned int uend,
                                           int lane, int s1lo, int s1hi) {
  float4* p4 = reinterpret_cast<float4*>(out);
  const float4 z4 = make_float4(0.f, 0.f, 0.f, 0.f);
  while (true) {
    unsigned int u = 0;
    if (lane == 0) u = atomicAdd(ctr, 1u);
    u = (unsigned int)__builtin_amdgcn_readfirstlane((int)u) + ubase;
    if (u >= uend) break;
    const int b4 = (int)u * 1280 + lane;
#pragma unroll
    for (int j = 0; j < 20; ++j) {
      const int i4 = b4 + j * 64;
      if (i4 >= s1lo && i4 < s1hi) continue;
      p4[i4] = z4;
    }
  }
}

// ---- cooperative: P1 gemm(256 tiles)||fill, grid.sync, P2 soft||fill --------
__global__ __launch_bounds__(256)
void k_coop(const float* __restrict__ x, const float* __restrict__ W,
            float* __restrict__ part, float2* __restrict__ g12,
            int* __restrict__ idxs, float* __restrict__ me_part,
            float* __restrict__ out, unsigned int* __restrict__ ctr,
            int s1lo, int s1hi) {
  __shared__ union {
    struct { float xs[BLKR][36]; float wt[32][68]; } g;  // gemm tiles
    float lg[64][33];                                    // soft gates
  } sh;
  const int tid = threadIdx.x;
  const int lane = tid & 63;
  // ---------------- P1: gemm role (R7-proven structure) ----------------
  if (blockIdx.x < 256) {
    const int rb = (int)blockIdx.x & 31;   // 32 row-blocks of 128 rows
    const int kc = (int)blockIdx.x >> 5;   // 8 k-chunks of 256
    const int r0 = rb * BLKR;
    const int er = tid & 15;
    const int rg = tid >> 4;
    float acc[8][4];
#pragma unroll
    for (int i = 0; i < 8; ++i)
#pragma unroll
      for (int c = 0; c < 4; ++c) acc[i][c] = 0.f;
    float4 sx[4], sw[2];
    {
      const int kb = kc * KCHUNK;
#pragma unroll
      for (int q = 0; q < 4; ++q) {
        const int li = tid + q * 256, row = li >> 3, kq = (li & 7) * 4;
        sx[q] = *reinterpret_cast<const float4*>(&x[(size_t)(r0 + row) * KDIM + kb + kq]);
      }
#pragma unroll
      for (int q = 0; q < 2; ++q) {
        const int li = tid + q * 256, e = li >> 3, kq = (li & 7) * 4;
        sw[q] = *reinterpret_cast<const float4*>(&W[(size_t)e * KDIM + kb + kq]);
      }
    }
    for (int s = 0; s < 8; ++s) {
      __syncthreads();
#pragma unroll
      for (int q = 0; q < 4; ++q) {
        const int li = tid + q * 256, row = li >> 3, kq = (li & 7) * 4;
        *reinterpret_cast<float4*>(&sh.g.xs[row][kq]) = sx[q];
      }
#pragma unroll
      for (int q = 0; q < 2; ++q) {
        const int li = tid + q * 256, e = li >> 3, kq = (li & 7) * 4;
        sh.g.wt[kq][e] = sw[q].x; sh.g.wt[kq + 1][e] = sw[q].y;
        sh.g.wt[kq + 2][e] = sw[q].z; sh.g.wt[kq + 3][e] = sw[q].w;
      }
      if (s < 7) {
        const int kb = kc * KCHUNK + (s + 1) * 32;
#pragma unroll
        for (int q = 0; q < 4; ++q) {
          const int li = tid + q * 256, row = li >> 3, kq = (li & 7) * 4;
          sx[q] = *reinterpret_cast<const float4*>(&x[(size_t)(r0 + row) * KDIM + kb + kq]);
        }
#pragma unroll
        for (int q = 0; q < 2; ++q) {
          const int li = tid + q * 256, e = li >> 3, kq = (li & 7) * 4;
          sw[q] = *reinterpret_cast<const float4*>(&W[(size_t)e * KDIM + kb + kq]);
        }
      }
      __syncthreads();
#pragma unroll
      for (int k4 = 0; k4 < 8; ++k4) {
        float4 wb[4];
#pragma unroll
        for (int j = 0; j < 4; ++j)
          wb[j] = *reinterpret_cast<const float4*>(&sh.g.wt[k4 * 4 + j][er * 4]);
#pragma unroll
        for (int i = 0; i < 8; ++i) {
          const float4 xv = *reinterpret_cast<const float4*>(&sh.g.xs[rg + 16 * i][k4 * 4]);
          // k-ascending nested fmaf: bitwise-identical to R5-R7
          acc[i][0] = fmaf(xv.w, wb[3].x, fmaf(xv.z, wb[2].x, fmaf(xv.y, wb[1].x, fmaf(xv.x, wb[0].x, acc[i][0]))));
          acc[i][1] = fmaf(xv.w, wb[3].y, fmaf(xv.z, wb[2].y, fmaf(xv.y, wb[1].y, fmaf(xv.x, wb[0].y, acc[i][1]))));
          acc[i][2] = fmaf(xv.w, wb[3].z, fmaf(xv.z, wb[2].z, fmaf(xv.y, wb[1].z, fmaf(xv.x, wb[0].z, acc[i][2]))));
          acc[i][3] = fmaf(xv.w, wb[3].w, fmaf(xv.z, wb[2].w, fmaf(xv.y, wb[1].w, fmaf(xv.x, wb[0].w, acc[i][3]))));
        }
      }
    }
#pragma unroll
    for (int i = 0; i < 8; ++i) {
      float4 v; v.x = acc[i][0]; v.y = acc[i][1]; v.z = acc[i][2]; v.w = acc[i][3];
      *reinterpret_cast<float4*>(
          &part[((size_t)kc * T_TOK + r0 + rg + 16 * i) * NE + er * 4]) = v;
    }
  }
  fill_units(out, ctr, 0u, UNITS - RESERVE_B, lane, s1lo, s1hi);
  __threadfence();
  cg::this_grid().sync();
  // ---------------- P2: softmax role (k_soft verbatim, 64 lanes) -------
  if (blockIdx.x < 128) {
    const int un = (int)blockIdx.x;
    if (tid < 64) {
      const int R = un * 64 + tid;
      const int t = R >> 1, p = R & 1;
      float v[32];
      const float* pr = part + (size_t)t * NE + p * EE;
#pragma unroll
      for (int e = 0; e < 32; e += 4) {
        const float4 s = *reinterpret_cast<const float4*>(pr + e);
        v[e] = s.x; v[e + 1] = s.y; v[e + 2] = s.z; v[e + 3] = s.w;
      }
      for (int kc = 1; kc < NKC; ++kc) {
        const float* prk = pr + (size_t)kc * T_TOK * NE;
#pragma unroll
        for (int e = 0; e < 32; e += 4) {
          const float4 s = *reinterpret_cast<const float4*>(prk + e);
          v[e] += s.x; v[e + 1] += s.y; v[e + 2] += s.z; v[e + 3] += s.w;
        }
      }
      float m = v[0];
#pragma unroll
      for (int e = 1; e < 32; ++e) m = fmaxf(m, v[e]);
      float sum = 0.f;
#pragma unroll
      for (int e = 0; e < 32; ++e) { v[e] = expf(v[e] - m); sum += v[e]; }
      const float inv = 1.0f / sum;
#pragma unroll
      for (int e = 0; e < 32; ++e) v[e] *= inv;
      float g1 = -1.f; int i1 = 0;
#pragma unroll
      for (int e = 0; e < 32; ++e) if (v[e] > g1) { g1 = v[e]; i1 = e; }
      float g2 = -1.f; int i2 = 0;
#pragma unroll
      for (int e = 0; e < 32; ++e) if (e != i1 && v[e] > g2) { g2 = v[e]; i2 = e; }
      g12[R] = make_float2(g1, g2);
      idxs[R] = i1 | (i2 << 8);
#pragma unroll
      for (int e = 0; e < 32; ++e) sh.lg[tid][e] = v[e];
    }
    __syncthreads();
    if (tid < 64) {
      const int pp = tid >> 5, ee = tid & 31;
      float s = 0.f;
      for (int rr = pp; rr < 64; rr += 2) s += sh.lg[rr][ee];
      me_part[un * 64 + tid] = s;
    }
    __syncthreads();
  }
  fill_units(out, ctr + 1, UNITS - RESERVE_B, UNITS, lane, s1lo, s1hi);
}

// ------- hierarchical ordered scans, 5-bit match trick (unchanged) -----------
__global__ __launch_bounds__(1024) void k_scan(const int* __restrict__ idxs,
                                               const float2* __restrict__ g12,
                                               const float* __restrict__ me_part,
                                               int2* __restrict__ fl,
                                               float2* __restrict__ wvp,
                                               float* __restrict__ out) {
  __shared__ int grp[NP][64][32];
  __shared__ int tot[NP][32];
  __shared__ unsigned short tk1[NP][T_TOK];
  __shared__ unsigned short tk2[NP][T_TOK];
  __shared__ float red[64];
  const int tid = threadIdx.x;
  const int wvi = tid >> 6;
  const int p = wvi >> 3;
  const int wg = wvi & 7;
  const int l = tid & 63;
  const unsigned long long lmask = (1ull << l) - 1ull;
  for (int gi = 0; gi < 8; ++gi) {
    const int g = wg * 8 + gi;
    const int t = g * 64 + l;
    const int e1 = idxs[t * 2 + p] & 255;
    if (l < 32) grp[p][g][l] = 0;
    unsigned long long m = ~0ull;
#pragma unroll
    for (int b = 0; b < 5; ++b) {
      const unsigned long long bm = __ballot((e1 >> b) & 1);
      m &= ((e1 >> b) & 1) ? bm : ~bm;
    }
    const int rank = (int)__popcll(m & lmask);
    if (rank == 0) grp[p][g][e1] = (int)__popcll(m);
    tk1[p][t] = (unsigned short)(rank | (e1 << 6));
  }
  __syncthreads();
  if (tid < 64) {
    const int pp = tid >> 5, ee = tid & 31;
    int s = 0;
    for (int g = 0; g < 64; ++g) { int vv = grp[pp][g][ee]; grp[pp][g][ee] = s; s += vv; }
    tot[pp][ee] = s;
  }
  __syncthreads();
  for (int gi = 0; gi < 8; ++gi) {
    const int g = wg * 8 + gi;
    const int t = g * 64 + l;
    const int vv = tk1[p][t];
    tk1[p][t] = (unsigned short)(grp[p][g][vv >> 6] + (vv & 63));
  }
  if (tid < 64) {
    float s = 0.f;
    for (int b = 0; b < 128; ++b) s += me_part[b * 64 + tid];
    red[tid] = s * (float)tot[tid >> 5][tid & 31];
  }
  __syncthreads();
  if (tid == 0) {
    float s = 0.f;
    for (int i = 0; i < 64; ++i) s += red[i];
    out[0] = s / (64.0f * 4096.0f * 4096.0f);
  }
  for (int gi = 0; gi < 8; ++gi) {
    const int g = wg * 8 + gi;
    const int t = g * 64 + l;
    const int ii = idxs[t * 2 + p];
    const int e2 = (tk1[p][t] < CAP) ? (ii >> 8) : (ii & 255);
    if (l < 32) grp[p][g][l] = 0;
    unsigned long long m = ~0ull;
#pragma unroll
    for (int b = 0; b < 5; ++b) {
      const unsigned long long bm = __ballot((e2 >> b) & 1);
      m &= ((e2 >> b) & 1) ? bm : ~bm;
    }
    const int rank = (int)__popcll(m & lmask);
    if (rank == 0) grp[p][g][e2] = (int)__popcll(m);
    tk2[p][t] = (unsigned short)(rank | (e2 << 6));
  }
  __syncthreads();
  if (tid < 64) {
    const int pp = tid >> 5, ee = tid & 31;
    int s = min(tot[pp][ee], CAP);
    for (int g = 0; g < 64; ++g) { int vv = grp[pp][g][ee]; grp[pp][g][ee] = s; s += vv; }
  }
  __syncthreads();
  for (int gi = 0; gi < 8; ++gi) {
    const int g = wg * 8 + gi;
    const int t = g * 64 + l;
    const int R = t * 2 + p;
    const int ii = idxs[R];
    const int e1 = ii & 255;
    const int loc1v = tk1[p][t];
    const bool kept1 = loc1v < CAP;
    const int v2 = tk2[p][t];
    const int rank2 = v2 & 63, e2 = v2 >> 6;
    const int loc2 = grp[p][g][e2] + rank2;
    const bool kept2 = loc2 < CAP;
    const float2 gg = g12[R];
    const float gs1 = kept1 ? gg.x : 0.f;
    const float g2v = kept1 ? gg.y : gg.x;
    const float gs2 = kept2 ? g2v : 0.f;
    const float den = fmaxf(gs1 + gs2, 1.1920929e-07f);
    fl[R] = make_int2(kept1 ? e1 * CAP + loc1v : -1, kept2 ? e2 * CAP + loc2 : -1);
    wvp[R] = make_float2(gs1 / den, gs2 / den);
  }
}

// ---- coop-path point fix (pre-zeroes the one uncovered last element) --------
__global__ __launch_bounds__(256) void k_fix2(const int2* __restrict__ fl,
                                              const float2* __restrict__ wvp,
                                              float* __restrict__ out) {
  const int R = blockIdx.x * 256 + threadIdx.x;
  const int2 f = fl[R];
  const float2 w = wvp[R];
  float* oc = out + 1 + (size_t)R * 5120;
  float* od = out + 1 + COMB_ELEMS + (size_t)R * 5120;
  if (R == 8191) od[5119] = 0.f;  // last elem not covered by f4 fill
  if (f.x >= 0) { oc[f.x] = w.x; od[f.x] = 1.0f; }
  if (f.y >= 0) { oc[f.y] = w.y; od[f.y] = 1.0f; }
}

// ---- pathB: zero the part window (tail of dispatch) after soft consumed it --
__global__ __launch_bounds__(256) void k_tailB(float* __restrict__ out) {
  float4* p4 = reinterpret_cast<float4*>(out);
  const float4 z4 = make_float4(0.f, 0.f, 0.f, 0.f);
  const int base = 20447232 + (int)blockIdx.x * 4096 + (int)threadIdx.x;
#pragma unroll
  for (int j = 0; j < 16; ++j) p4[base + j * 256] = z4;
  if (blockIdx.x == 0 && threadIdx.x == 0) out[OUT_ELEMS - 1] = 0.f;
}

// ======================= R7 fallback chain (proven 104us) ====================
__global__ __launch_bounds__(256) void k_fusedF(const float* __restrict__ x,
                                                const float* __restrict__ W,
                                                float* __restrict__ part,
                                                float* __restrict__ out,
                                                int s1lo, int s1hi, int s2lo, int s2hi,
                                                int fillLast) {
  __shared__ float xs[BLKR][36];
  __shared__ float wt[32][68];
  const int tid = threadIdx.x;
  if (blockIdx.x >= 256) {
    const int fb = blockIdx.x - 256;
    float4* p4 = reinterpret_cast<float4*>(out);
    const float4 z4 = make_float4(0.f, 0.f, 0.f, 0.f);
    const int start = fb * 5120;
#pragma unroll
    for (int j = 0; j < 20; ++j) {
      const int i4 = start + tid + j * 256;
      if (i4 >= s1lo && i4 < s1hi) continue;
      if (i4 >= s2lo && i4 < s2hi) continue;
      p4[i4] = z4;
    }
    if (fillLast && fb == NFB - 1 && tid == 255) out[OUT_ELEMS - 1] = 0.f;
    return;
  }
  const int rb = blockIdx.x & 31;
  const int kc = blockIdx.x >> 5;
  const int r0 = rb * BLKR;
  const int er = tid & 15;
  const int rg = tid >> 4;
  float acc[8][4];
#pragma unroll
  for (int i = 0; i < 8; ++i)
#pragma unroll
    for (int c = 0; c < 4; ++c) acc[i][c] = 0.f;
  float4 sx[4], sw[2];
  {
    const int kb = kc * KCHUNK;
#pragma unroll
    for (int q = 0; q < 4; ++q) {
      const int li = tid + q * 256, row = li >> 3, kq = (li & 7) * 4;
      sx[q] = *reinterpret_cast<const float4*>(&x[(size_t)(r0 + row) * KDIM + kb + kq]);
    }
#pragma unroll
    for (int q = 0; q < 2; ++q) {
      const int li = tid + q * 256, e = li >> 3, kq = (li & 7) * 4;
      sw[q] = *reinterpret_cast<const float4*>(&W[(size_t)e * KDIM + kb + kq]);
    }
  }
  for (int s = 0; s < 8; ++s) {
    __syncthreads();
#pragma unroll
    for (int q = 0; q < 4; ++q) {
      const int li = tid + q * 256, row = li >> 3, kq = (li & 7) * 4;
      *reinterpret_cast<float4*>(&xs[row][kq]) = sx[q];
    }
#pragma unroll
    for (int q = 0; q < 2; ++q) {
      const int li = tid + q * 256, e = li >> 3, kq = (li & 7) * 4;
      wt[kq][e] = sw[q].x; wt[kq + 1][e] = sw[q].y;
      wt[kq + 2][e] = sw[q].z; wt[kq + 3][e] = sw[q].w;
    }
    if (s < 7) {
      const int kb = kc * KCHUNK + (s + 1) * 32;
#pragma unroll
      for (int q = 0; q < 4; ++q) {
        const int li = tid + q * 256, row = li >> 3, kq = (li & 7) * 4;
        sx[q] = *reinterpret_cast<const float4*>(&x[(size_t)(r0 + row) * KDIM + kb + kq]);
      }
#pragma unroll
      for (int q = 0; q < 2; ++q) {
        const int li = tid + q * 256, e = li >> 3, kq = (li & 7) * 4;
        sw[q] = *reinterpret_cast<const float4*>(&W[(size_t)e * KDIM + kb + kq]);
      }
    }
    __syncthreads();
#pragma unroll
    for (int k4 = 0; k4 < 8; ++k4) {
      float4 wb[4];
#pragma unroll
      for (int j = 0; j < 4; ++j)
        wb[j] = *reinterpret_cast<const float4*>(&wt[k4 * 4 + j][er * 4]);
#pragma unroll
      for (int i = 0; i < 8; ++i) {
        const float4 xv = *reinterpret_cast<const float4*>(&xs[rg + 16 * i][k4 * 4]);
        acc[i][0] = fmaf(xv.w, wb[3].x, fmaf(xv.z, wb[2].x, fmaf(xv.y, wb[1].x, fmaf(xv.x, wb[0].x, acc[i][0]))));
        acc[i][1] = fmaf(xv.w, wb[3].y, fmaf(xv.z, wb[2].y, fmaf(xv.y, wb[1].y, fmaf(xv.x, wb[0].y, acc[i][1]))));
        acc[i][2] = fmaf(xv.w, wb[3].z, fmaf(xv.z, wb[2].z, fmaf(xv.y, wb[1].z, fmaf(xv.x, wb[0].z, acc[i][2]))));
        acc[i][3] = fmaf(xv.w, wb[3].w, fmaf(xv.z, wb[2].w, fmaf(xv.y, wb[1].w, fmaf(xv.x, wb[0].w, acc[i][3]))));
      }
    }
  }
#pragma unroll
  for (int i = 0; i < 8; ++i) {
    float4 v; v.x = acc[i][0]; v.y = acc[i][1]; v.z = acc[i][2]; v.w = acc[i][3];
    *reinterpret_cast<float4*>(
        &part[((size_t)kc * T_TOK + r0 + rg + 16 * i) * NE + er * 4]) = v;
  }
}

__global__ __launch_bounds__(256) void k_fill2F(float* __restrict__ out) {
  float4* p4 = reinterpret_cast<float4*>(out + 4);
  const float4 z4 = make_float4(0.f, 0.f, 0.f, 0.f);
  const int base = blockIdx.x * 2048 + threadIdx.x;
#pragma unroll
  for (int j = 0; j < 8; ++j) p4[base + j * 256] = z4;
}

__global__ __launch_bounds__(64) void k_softF(const float* __restrict__ part,
                                              float2* __restrict__ g12,
                                              int* __restrict__ idxs,
                                              float* __restrict__ me_part) {
  __shared__ float lg[64][33];
  const int tid = threadIdx.x;
  const int R = blockIdx.x * 64 + tid;
  const int t = R >> 1;
  const int p = R & 1;
  float v[32];
  const float* pr = part + (size_t)t * NE + p * EE;
#pragma unroll
  for (int e = 0; e < 32; e += 4) {
    float4 s = *reinterpret_cast<const float4*>(pr + e);
    v[e] = s.x; v[e + 1] = s.y; v[e + 2] = s.z; v[e + 3] = s.w;
  }
  for (int kc = 1; kc < NKC; ++kc) {
    const float* prk = pr + (size_t)kc * T_TOK * NE;
#pragma unroll
    for (int e = 0; e < 32; e += 4) {
      float4 s = *reinterpret_cast<const float4*>(prk + e);
      v[e] += s.x; v[e + 1] += s.y; v[e + 2] += s.z; v[e + 3] += s.w;
    }
  }
  float m = v[0];
#pragma unroll
  for (int e = 1; e < 32; ++e) m = fmaxf(m, v[e]);
  float sum = 0.f;
#pragma unroll
  for (int e = 0; e < 32; ++e) { v[e] = expf(v[e] - m); sum += v[e]; }
  const float inv = 1.0f / sum;
#pragma unroll
  for (int e = 0; e < 32; ++e) v[e] *= inv;
  float g1 = -1.f; int i1 = 0;
#pragma unroll
  for (int e = 0; e < 32; ++e) if (v[e] > g1) { g1 = v[e]; i1 = e; }
  float g2 = -1.f; int i2 = 0;
#pragma unroll
  for (int e = 0; e < 32; ++e) if (e != i1 && v[e] > g2) { g2 = v[e]; i2 = e; }
  g12[R] = make_float2(g1, g2);
  idxs[R] = i1 | (i2 << 8);
#pragma unroll
  for (int e = 0; e < 32; ++e) lg[tid][e] = v[e];
  __syncthreads();
  {
    const int pp = tid >> 5, ee = tid & 31;
    float s = 0.f;
    for (int rr = pp; rr < 64; rr += 2) s += lg[rr][ee];
    me_part[blockIdx.x * 64 + tid] = s;
  }
}

__global__ __launch_bounds__(256) void k_fixF(const int2* __restrict__ fl,
                                              const float2* __restrict__ wvp,
                                              float* __restrict__ out,
                                              int rlimit) {
  const int R = blockIdx.x * 256 + threadIdx.x;
  const int2 f = fl[R];
  const float2 w = wvp[R];
  float* oc = out + 1 + (size_t)R * 5120;
  if (f.x >= 0) oc[f.x] = w.x;
  if (f.y >= 0) oc[f.y] = w.y;
  if (R < rlimit) {
    float* od = out + 1 + COMB_ELEMS + (size_t)R * 5120;
    if (f.x >= 0) od[f.x] = 1.0f;
    if (f.y >= 0) od[f.y] = 1.0f;
  }
}

__global__ __launch_bounds__(1024) void k_tailF(const int2* __restrict__ fl,
                                                float* __restrict__ out,
                                                int nfullB) {
  __shared__ int2 sfl[16];
  const int tid = threadIdx.x;
  const int rstart = nfullB * 2;
  const int nr = 8192 - rstart;
  if (tid < nr) sfl[tid] = fl[rstart + tid];
  __syncthreads();
  const size_t base = 1 + COMB_ELEMS + (size_t)rstart * 5120;
  const int cnt = nr * 5120;
  const int nx4 = (cnt - 4) >> 2;
  float4* p4 = (float4*)(out + base + 3);
  const float4 z4 = make_float4(0.f, 0.f, 0.f, 0.f);
  for (int idx = tid; idx < nx4; idx += 1024) p4[idx] = z4;
  if (tid < 3) out[base + tid] = 0.f;
  if (tid == 3) out[base + cnt - 1] = 0.f;
  __syncthreads();
  if (tid < 2 * nr) {
    const int rr = rstart + (tid >> 1);
    const int2 f = sfl[tid >> 1];
    const int pos = (tid & 1) ? f.y : f.x;
    if (pos >= 0) out[1 + COMB_ELEMS + (size_t)rr * 5120 + pos] = 1.0f;
  }
}

static void launch_fallback(const float* x, const float* W, float* out,
                            void* d_ws, size_t ws_size, hipStream_t stream) {
  float* small;
  float* part;
  int s1lo = 0, s1hi = 0, s2lo = 0, s2hi = 0, fillLast = 1;
  bool needFill2 = false;
  int nfullB = 4096, rlimit = 8192;
  if (ws_size >= (SMALLF + PARTF) * sizeof(float)) {
    small = (float*)d_ws;
    part = small + SMALLF;
  } else if (ws_size >= SMALLF * sizeof(float)) {
    small = (float*)d_ws;
    part = out + 4;
    s1lo = 1; s1hi = 1 + (int)(PARTF / 4);
    needFill2 = true;
  } else {
    const size_t tb = (OUT_ELEMS - SMALLF) & ~(size_t)3;
    small = out + tb;
    part = out + 4;
    s1lo = 1; s1hi = 1 + (int)(PARTF / 4);
    s2lo = (int)(tb / 4); s2hi = TOT4;
    fillLast = 0;
    needFill2 = true;
    nfullB = (int)((tb - 1 - COMB_ELEMS) / 10240);
    rlimit = nfullB * 2;
  }
  float2* g12 = (float2*)small;
  int* idxs = (int*)(small + 16384);
  float* me_part = small + 24576;
  int2* fl = (int2*)(small + 32768);
  float2* wvp = (float2*)(small + 49152);
  hipLaunchKernelGGL(k_fusedF, dim3(256 + NFB), dim3(256), 0, stream,
                     x, W, part, out, s1lo, s1hi, s2lo, s2hi, fillLast);
  hipLaunchKernelGGL(k_softF, dim3(128), dim3(64), 0, stream, part, g12, idxs, me_part);
  if (needFill2)
    hipLaunchKernelGGL(k_fill2F, dim3(256), dim3(256), 0, stream, out);
  hipLaunchKernelGGL(k_scan, dim3(1), dim3(1024), 0, stream, idxs, g12, me_part, fl, wvp, out);
  hipLaunchKernelGGL(k_fixF, dim3(32), dim3(256), 0, stream, fl, wvp, out, rlimit);
  if (nfullB < 4096)
    hipLaunchKernelGGL(k_tailF, dim3(1), dim3(1024), 0, stream, fl, out, nfullB);
}

extern "C" void kernel_launch(void* const* d_in, const int* in_sizes, int n_in,
                              void* d_out, int out_size, void* d_ws, size_t ws_size,
                              hipStream_t stream) {
  const float* x = (const float*)d_in[0];
  const float* W = (const float*)d_in[1];
  float* out = (float*)d_out;

  const bool pathA = ws_size >= (SMALLF + PARTF) * sizeof(float);
  const bool pathB = !pathA && ws_size >= SMALLF * sizeof(float);
  if (!pathA && !pathB) { launch_fallback(x, W, out, d_ws, ws_size, stream); return; }

  float* small = (float*)d_ws;
  float* part = pathA ? (small + SMALLF) : (out + PB_F);
  const int s1lo = pathA ? 0 : 20447232;
  const int s1hi = pathA ? 0 : TOT4;
  float2* g12 = (float2*)small;
  int* idxs = (int*)(small + 16384);
  float* me_part = small + 24576;
  int2* fl = (int2*)(small + 32768);
  float2* wvp = (float2*)(small + 49152);
  unsigned int* ctr = (unsigned int*)(small + 65536);

  hipMemsetAsync(ctr, 0, 8, stream);
  int nb = 0;
  hipError_t oe = hipOccupancyMaxActiveBlocksPerMultiprocessor(&nb, k_coop, 256, 0);
  int G = (oe == hipSuccess && nb > 0) ? nb * 256 : 256;
  if (G > 2048) G = 2048;
  void* args[] = {(void*)&x, (void*)&W, (void*)&part, (void*)&g12, (void*)&idxs,
                  (void*)&me_part, (void*)&out, (void*)&ctr,
                  (void*)&s1lo, (void*)&s1hi};
  hipError_t ce = hipLaunchCooperativeKernel((const void*)k_coop, dim3(G), dim3(256),
                                             args, 0, stream);
  if (ce != hipSuccess) { launch_fallback(x, W, out, d_ws, ws_size, stream); return; }

  hipLaunchKernelGGL(k_scan, dim3(1), dim3(1024), 0, stream, idxs, g12, me_part, fl, wvp, out);
  if (pathB)
    hipLaunchKernelGGL(k_tailB, dim3(128), dim3(256), 0, stream, out);
  hipLaunchKernelGGL(k_fix2, dim3(32), dim3(256), 0, stream, fl, wvp, out);
}

// Round 10
// 164.133 us; speedup vs baseline: 2.1575x; 2.1575x over previous
//
#include <hip/hip_runtime.h>
#include <cstdint>

#define T_TOK 4096
#define KDIM 2048
#define NE 64
#define NP 2
#define EE 32
#define CAP 160
#define NKC 8
#define KCHUNK 256
#define BLKR 128
#define COMB_ELEMS 41943040ull /* 8192 * 5120 */
#define OUT_ELEMS 83886081ull  /* 1 + 2*COMB */
#define PARTF 2097152ull
#define TOT4 20971520          /* float4s covering OUT_ELEMS-1 */
#define NFB 4096
#define SMALLF 59424           /* g12 16384 | idxs 8192 | me 2048 | fl 16384 | wvp 16384 | tk 32 */
#define PB_F 81788928          /* pathB part offset (f4 20447232) */

// ---- mega: blocks 0..255 gemm(+ticket soft), 256..4351 static zero-fill ----
__global__ __launch_bounds__(256)
void k_mega(const float* __restrict__ x, const float* __restrict__ W,
            float* __restrict__ part, float2* __restrict__ g12,
            int* __restrict__ idxs, float* __restrict__ me_part,
            float* __restrict__ out, unsigned int* __restrict__ tickets,
            int s1lo, int s1hi, int s2lo, int s2hi, int fillLast) {
  __shared__ union {
    struct { float xs[BLKR][36]; float wt[32][68]; } g;  // gemm tiles
    float lg[256][33];                                   // soft gates
  } sh;
  __shared__ int iswin;
  const int tid = threadIdx.x;
  if (blockIdx.x >= 256) {  // ---------- static fill role (R7-proven) --------
    const int fb = (int)blockIdx.x - 256;
    float4* p4 = reinterpret_cast<float4*>(out);
    const float4 z4 = make_float4(0.f, 0.f, 0.f, 0.f);
    const int start = fb * 5120;
#pragma unroll
    for (int j = 0; j < 20; ++j) {
      const int i4 = start + tid + j * 256;
      if (i4 >= s1lo && i4 < s1hi) continue;
      if (i4 >= s2lo && i4 < s2hi) continue;
      p4[i4] = z4;
    }
    if (fillLast && fb == NFB - 1 && tid == 255) out[OUT_ELEMS - 1] = 0.f;
    return;
  }
  // ---------- gemm role (R7-verbatim math) ----------
  const int rb = (int)blockIdx.x & 31;
  const int kc = (int)blockIdx.x >> 5;
  const int r0 = rb * BLKR;
  const int er = tid & 15;
  const int rg = tid >> 4;
  float acc[8][4];
#pragma unroll
  for (int i = 0; i < 8; ++i)
#pragma unroll
    for (int c = 0; c < 4; ++c) acc[i][c] = 0.f;
  float4 sx[4], sw[2];
  {
    const int kb = kc * KCHUNK;
#pragma unroll
    for (int q = 0; q < 4; ++q) {
      const int li = tid + q * 256, row = li >> 3, kq = (li & 7) * 4;
      sx[q] = *reinterpret_cast<const float4*>(&x[(size_t)(r0 + row) * KDIM + kb + kq]);
    }
#pragma unroll
    for (int q = 0; q < 2; ++q) {
      const int li = tid + q * 256, e = li >> 3, kq = (li & 7) * 4;
      sw[q] = *reinterpret_cast<const float4*>(&W[(size_t)e * KDIM + kb + kq]);
    }
  }
  for (int s = 0; s < 8; ++s) {
    __syncthreads();
#pragma unroll
    for (int q = 0; q < 4; ++q) {
      const int li = tid + q * 256, row = li >> 3, kq = (li & 7) * 4;
      *reinterpret_cast<float4*>(&sh.g.xs[row][kq]) = sx[q];
    }
#pragma unroll
    for (int q = 0; q < 2; ++q) {
      const int li = tid + q * 256, e = li >> 3, kq = (li & 7) * 4;
      sh.g.wt[kq][e] = sw[q].x; sh.g.wt[kq + 1][e] = sw[q].y;
      sh.g.wt[kq + 2][e] = sw[q].z; sh.g.wt[kq + 3][e] = sw[q].w;
    }
    if (s < 7) {
      const int kb = kc * KCHUNK + (s + 1) * 32;
#pragma unroll
      for (int q = 0; q < 4; ++q) {
        const int li = tid + q * 256, row = li >> 3, kq = (li & 7) * 4;
        sx[q] = *reinterpret_cast<const float4*>(&x[(size_t)(r0 + row) * KDIM + kb + kq]);
      }
#pragma unroll
      for (int q = 0; q < 2; ++q) {
        const int li = tid + q * 256, e = li >> 3, kq = (li & 7) * 4;
        sw[q] = *reinterpret_cast<const float4*>(&W[(size_t)e * KDIM + kb + kq]);
      }
    }
    __syncthreads();
#pragma unroll
    for (int k4 = 0; k4 < 8; ++k4) {
      float4 wb[4];
#pragma unroll
      for (int j = 0; j < 4; ++j)
        wb[j] = *reinterpret_cast<const float4*>(&sh.g.wt[k4 * 4 + j][er * 4]);
#pragma unroll
      for (int i = 0; i < 8; ++i) {
        const float4 xv = *reinterpret_cast<const float4*>(&sh.g.xs[rg + 16 * i][k4 * 4]);
        acc[i][0] = fmaf(xv.w, wb[3].x, fmaf(xv.z, wb[2].x, fmaf(xv.y, wb[1].x, fmaf(xv.x, wb[0].x, acc[i][0]))));
        acc[i][1] = fmaf(xv.w, wb[3].y, fmaf(xv.z, wb[2].y, fmaf(xv.y, wb[1].y, fmaf(xv.x, wb[0].y, acc[i][1]))));
        acc[i][2] = fmaf(xv.w, wb[3].z, fmaf(xv.z, wb[2].z, fmaf(xv.y, wb[1].z, fmaf(xv.x, wb[0].z, acc[i][2]))));
        acc[i][3] = fmaf(xv.w, wb[3].w, fmaf(xv.z, wb[2].w, fmaf(xv.y, wb[1].w, fmaf(xv.x, wb[0].w, acc[i][3]))));
      }
    }
  }
#pragma unroll
  for (int i = 0; i < 8; ++i) {
    float4 v; v.x = acc[i][0]; v.y = acc[i][1]; v.z = acc[i][2]; v.w = acc[i][3];
    *reinterpret_cast<float4*>(
        &part[((size_t)kc * T_TOK + r0 + rg + 16 * i) * NE + er * 4]) = v;
  }
  // ---- low-frequency ticket: 8 increments per rowblock; 8th runs softmax ----
  __threadfence();  // release: partials visible device-wide
  if (tid == 0) iswin = (atomicAdd(&tickets[rb], 1u) == 7u);
  __syncthreads();
  if (!iswin) return;
  __threadfence();  // acquire: see all 8 kc-blocks' partials
  {  // soft for rows r0..r0+127 (ops verbatim from R7 k_soft)
    const int row = tid >> 1, p = tid & 1;
    const int t = r0 + row;
    const int R = t * 2 + p;
    float v[32];
    const float* pr = part + (size_t)t * NE + p * EE;
#pragma unroll
    for (int e = 0; e < 32; e += 4) {
      const float4 sv = *reinterpret_cast<const float4*>(pr + e);
      v[e] = sv.x; v[e + 1] = sv.y; v[e + 2] = sv.z; v[e + 3] = sv.w;
    }
    for (int kc2 = 1; kc2 < NKC; ++kc2) {
      const float* prk = pr + (size_t)kc2 * T_TOK * NE;
#pragma unroll
      for (int e = 0; e < 32; e += 4) {
        const float4 sv = *reinterpret_cast<const float4*>(prk + e);
        v[e] += sv.x; v[e + 1] += sv.y; v[e + 2] += sv.z; v[e + 3] += sv.w;
      }
    }
    float m = v[0];
#pragma unroll
    for (int e = 1; e < 32; ++e) m = fmaxf(m, v[e]);
    float sum = 0.f;
#pragma unroll
    for (int e = 0; e < 32; ++e) { v[e] = expf(v[e] - m); sum += v[e]; }
    const float inv = 1.0f / sum;
#pragma unroll
    for (int e = 0; e < 32; ++e) v[e] *= inv;
    float g1 = -1.f; int i1 = 0;
#pragma unroll
    for (int e = 0; e < 32; ++e) if (v[e] > g1) { g1 = v[e]; i1 = e; }  // first-max
    float g2 = -1.f; int i2 = 0;
#pragma unroll
    for (int e = 0; e < 32; ++e) if (e != i1 && v[e] > g2) { g2 = v[e]; i2 = e; }
    g12[R] = make_float2(g1, g2);
    idxs[R] = i1 | (i2 << 8);
    __syncthreads();  // union switch g -> lg
#pragma unroll
    for (int e = 0; e < 32; ++e) sh.lg[tid][e] = v[e];
  }
  __syncthreads();
  if (tid < 64) {  // me partial per (p,e), tokens ascending
    const int pp = tid >> 5, ee = tid & 31;
    float s = 0.f;
    for (int rr = 0; rr < 128; ++rr) s += sh.lg[rr * 2 + pp][ee];
    me_part[rb * 64 + tid] = s;
  }
}

// ------- scan (R6-proven) + inline point-fixes + l_aux ----------------------
__global__ __launch_bounds__(1024) void k_scan2(const int* __restrict__ idxs,
                                                const float2* __restrict__ g12,
                                                const float* __restrict__ me_part,
                                                int2* __restrict__ fl,
                                                float2* __restrict__ wvp,
                                                float* __restrict__ out,
                                                int rlimit) {
  __shared__ int grp[NP][64][32];
  __shared__ int tot[NP][32];
  __shared__ unsigned short tk1[NP][T_TOK];
  __shared__ unsigned short tk2[NP][T_TOK];
  __shared__ float red[64];
  const int tid = threadIdx.x;
  const int wvi = tid >> 6;
  const int p = wvi >> 3;
  const int wg = wvi & 7;
  const int l = tid & 63;
  const unsigned long long lmask = (1ull << l) - 1ull;
  for (int gi = 0; gi < 8; ++gi) {
    const int g = wg * 8 + gi;
    const int t = g * 64 + l;
    const int e1 = idxs[t * 2 + p] & 255;
    if (l < 32) grp[p][g][l] = 0;
    unsigned long long m = ~0ull;
#pragma unroll
    for (int b = 0; b < 5; ++b) {
      const unsigned long long bm = __ballot((e1 >> b) & 1);
      m &= ((e1 >> b) & 1) ? bm : ~bm;
    }
    const int rank = (int)__popcll(m & lmask);
    if (rank == 0) grp[p][g][e1] = (int)__popcll(m);
    tk1[p][t] = (unsigned short)(rank | (e1 << 6));
  }
  __syncthreads();
  if (tid < 64) {
    const int pp = tid >> 5, ee = tid & 31;
    int s = 0;
    for (int g = 0; g < 64; ++g) { int vv = grp[pp][g][ee]; grp[pp][g][ee] = s; s += vv; }
    tot[pp][ee] = s;
  }
  __syncthreads();
  for (int gi = 0; gi < 8; ++gi) {
    const int g = wg * 8 + gi;
    const int t = g * 64 + l;
    const int vv = tk1[p][t];
    tk1[p][t] = (unsigned short)(grp[p][g][vv >> 6] + (vv & 63));
  }
  if (tid < 64) {
    float s = 0.f;
    for (int b = 0; b < 32; ++b) s += me_part[b * 64 + tid];  // 32 rowblocks
    red[tid] = s * (float)tot[tid >> 5][tid & 31];
  }
  __syncthreads();
  if (tid == 0) {
    float s = 0.f;
    for (int i = 0; i < 64; ++i) s += red[i];
    out[0] = s / (64.0f * 4096.0f * 4096.0f);
  }
  for (int gi = 0; gi < 8; ++gi) {
    const int g = wg * 8 + gi;
    const int t = g * 64 + l;
    const int ii = idxs[t * 2 + p];
    const int e2 = (tk1[p][t] < CAP) ? (ii >> 8) : (ii & 255);
    if (l < 32) grp[p][g][l] = 0;
    unsigned long long m = ~0ull;
#pragma unroll
    for (int b = 0; b < 5; ++b) {
      const unsigned long long bm = __ballot((e2 >> b) & 1);
      m &= ((e2 >> b) & 1) ? bm : ~bm;
    }
    const int rank = (int)__popcll(m & lmask);
    if (rank == 0) grp[p][g][e2] = (int)__popcll(m);
    tk2[p][t] = (unsigned short)(rank | (e2 << 6));
  }
  __syncthreads();
  if (tid < 64) {
    const int pp = tid >> 5, ee = tid & 31;
    int s = min(tot[pp][ee], CAP);
    for (int g = 0; g < 64; ++g) { int vv = grp[pp][g][ee]; grp[pp][g][ee] = s; s += vv; }
  }
  __syncthreads();
  for (int gi = 0; gi < 8; ++gi) {
    const int g = wg * 8 + gi;
    const int t = g * 64 + l;
    const int R = t * 2 + p;
    const int ii = idxs[R];
    const int e1 = ii & 255;
    const int loc1v = tk1[p][t];
    const bool kept1 = loc1v < CAP;
    const int v2 = tk2[p][t];
    const int rank2 = v2 & 63, e2 = v2 >> 6;
    const int loc2 = grp[p][g][e2] + rank2;
    const bool kept2 = loc2 < CAP;
    const float2 gg = g12[R];
    const float gs1 = kept1 ? gg.x : 0.f;
    const float g2v = kept1 ? gg.y : gg.x;
    const float gs2 = kept2 ? g2v : 0.f;
    const float den = fmaxf(gs1 + gs2, 1.1920929e-07f);  // FLT_EPSILON
    const int f1 = kept1 ? e1 * CAP + loc1v : -1;
    const int f2 = kept2 ? e2 * CAP + loc2 : -1;
    const float w1 = gs1 / den, w2 = gs2 / den;
    fl[R] = make_int2(f1, f2);
    wvp[R] = make_float2(w1, w2);
    float* oc = out + 1 + (size_t)R * 5120;         // fixes: zeros already down
    if (f1 >= 0) oc[f1] = w1;
    if (f2 >= 0) oc[f2] = w2;
    if (R < rlimit) {
      float* od = out + 1 + COMB_ELEMS + (size_t)R * 5120;
      if (f1 >= 0) od[f1] = 1.0f;
      if (f2 >= 0) od[f2] = 1.0f;
    }
  }
}

// pathB: zero the part window (tail of dispatch) after soft consumed it
__global__ __launch_bounds__(256) void k_tailB(float* __restrict__ out) {
  float4* p4 = reinterpret_cast<float4*>(out);
  const float4 z4 = make_float4(0.f, 0.f, 0.f, 0.f);
  const int base = 20447232 + (int)blockIdx.x * 4096 + (int)threadIdx.x;
#pragma unroll
  for (int j = 0; j < 16; ++j) p4[base + j * 256] = z4;
  if (blockIdx.x == 0 && threadIdx.x == 0) out[OUT_ELEMS - 1] = 0.f;
}

// pathC: zero the part window at combine front (after soft consumed it)
__global__ __launch_bounds__(256) void k_fill2C(float* __restrict__ out) {
  float4* p4 = reinterpret_cast<float4*>(out + 4);
  const float4 z4 = make_float4(0.f, 0.f, 0.f, 0.f);
  const int base = (int)blockIdx.x * 2048 + (int)threadIdx.x;
#pragma unroll
  for (int j = 0; j < 8; ++j) p4[base + j * 256] = z4;
}

// pathC: zero dispatch-tail scratch window + its rows' fixes (from fl)
__global__ __launch_bounds__(1024) void k_tailC(const int2* __restrict__ fl,
                                                float* __restrict__ out,
                                                int nfullB) {
  __shared__ int2 sfl[16];
  const int tid = threadIdx.x;
  const int rstart = nfullB * 2;
  const int nr = 8192 - rstart;  // <= 16
  if (tid < nr) sfl[tid] = fl[rstart + tid];
  __syncthreads();
  const size_t base = 1 + COMB_ELEMS + (size_t)rstart * 5120;
  const int cnt = nr * 5120;
  const int nx4 = (cnt - 4) >> 2;
  float4* p4 = (float4*)(out + base + 3);
  const float4 z4 = make_float4(0.f, 0.f, 0.f, 0.f);
  for (int idx = tid; idx < nx4; idx += 1024) p4[idx] = z4;
  if (tid < 3) out[base + tid] = 0.f;
  if (tid == 3) out[base + cnt - 1] = 0.f;
  __syncthreads();
  if (tid < 2 * nr) {
    const int rr = rstart + (tid >> 1);
    const int2 f = sfl[tid >> 1];
    const int pos = (tid & 1) ? f.y : f.x;
    if (pos >= 0) out[1 + COMB_ELEMS + (size_t)rr * 5120 + pos] = 1.0f;
  }
}

extern "C" void kernel_launch(void* const* d_in, const int* in_sizes, int n_in,
                              void* d_out, int out_size, void* d_ws, size_t ws_size,
                              hipStream_t stream) {
  const float* x = (const float*)d_in[0];
  const float* W = (const float*)d_in[1];
  float* out = (float*)d_out;

  const bool pathA = ws_size >= (SMALLF + PARTF) * sizeof(float);
  const bool pathB = !pathA && ws_size >= SMALLF * sizeof(float);

  float* small;
  float* part;
  int s1lo = 0, s1hi = 0, s2lo = 0, s2hi = 0, fillLast = 1;
  int rlimit = 8192, nfullB = 4096;
  if (pathA) {
    small = (float*)d_ws;
    part = small + SMALLF;
  } else if (pathB) {
    small = (float*)d_ws;
    part = out + PB_F;
    s1lo = PB_F / 4; s1hi = TOT4;           // part window in dispatch tail
    fillLast = 0;                            // tailB handles last elem
  } else {
    const size_t tb = (OUT_ELEMS - SMALLF) & ~(size_t)3;  // 83826656
    small = out + tb;
    part = out + 4;
    s1lo = 1; s1hi = 1 + (int)(PARTF / 4);   // part window at combine front
    s2lo = (int)(tb / 4); s2hi = TOT4;       // scratch window at tail
    fillLast = 0;
    nfullB = (int)((tb - 1 - COMB_ELEMS) / 10240);  // 4090
    rlimit = nfullB * 2;
  }
  float2* g12 = (float2*)small;
  int* idxs = (int*)(small + 16384);
  float* me_part = small + 24576;
  int2* fl = (int2*)(small + 26624);
  float2* wvp = (float2*)(small + 43008);
  unsigned int* tickets = (unsigned int*)(small + 59392);

  hipMemsetAsync(tickets, 0, 32 * sizeof(unsigned int), stream);
  hipLaunchKernelGGL(k_mega, dim3(256 + NFB), dim3(256), 0, stream,
                     x, W, part, g12, idxs, me_part, out, tickets,
                     s1lo, s1hi, s2lo, s2hi, fillLast);
  if (pathB)
    hipLaunchKernelGGL(k_tailB, dim3(128), dim3(256), 0, stream, out);
  if (!pathA && !pathB)
    hipLaunchKernelGGL(k_fill2C, dim3(256), dim3(256), 0, stream, out);
  hipLaunchKernelGGL(k_scan2, dim3(1), dim3(1024), 0, stream,
                     idxs, g12, me_part, fl, wvp, out, rlimit);
  if (!pathA && !pathB)
    hipLaunchKernelGGL(k_tailC, dim3(1), dim3(1024), 0, stream, fl, out, nfullB);
}

// Round 11
// 124.531 us; speedup vs baseline: 2.8436x; 1.3180x over previous
//
#include <hip/hip_runtime.h>
#include <cstdint>

#define T_TOK 4096
#define KDIM 2048
#define NE 64
#define NP 2
#define EE 32
#define CAP 160
#define NKC 8
#define KCHUNK 256
#define BLKR 128
#define COMB_ELEMS 41943040ull /* 8192 * 5120 */
#define OUT_ELEMS 83886081ull  /* 1 + 2*COMB */
#define PARTF 2097152ull
#define TOT4 20971520          /* float4s covering OUT_ELEMS-1 */
#define NFB 4096
#define SMALLF 65536           /* g12 16384 | idxs 8192 | me 8192 | fl 16384 | wvp 16384 */
#define PB_F 81788928          /* pathB part offset (f4 20447232) */

// ---------------- GEMM standalone (R6/R7-proven, verbatim math) --------------
__global__ __launch_bounds__(256) void k_gemm(const float* __restrict__ x,
                                              const float* __restrict__ W,
                                              float* __restrict__ part) {
  __shared__ float xs[BLKR][36];
  __shared__ float wt[32][68];
  const int tid = threadIdx.x;
  const int rb = (int)blockIdx.x & 31;
  const int kc = (int)blockIdx.x >> 5;
  const int r0 = rb * BLKR;
  const int er = tid & 15;
  const int rg = tid >> 4;
  float acc[8][4];
#pragma unroll
  for (int i = 0; i < 8; ++i)
#pragma unroll
    for (int c = 0; c < 4; ++c) acc[i][c] = 0.f;
  float4 sx[4], sw[2];
  {
    const int kb = kc * KCHUNK;
#pragma unroll
    for (int q = 0; q < 4; ++q) {
      const int li = tid + q * 256, row = li >> 3, kq = (li & 7) * 4;
      sx[q] = *reinterpret_cast<const float4*>(&x[(size_t)(r0 + row) * KDIM + kb + kq]);
    }
#pragma unroll
    for (int q = 0; q < 2; ++q) {
      const int li = tid + q * 256, e = li >> 3, kq = (li & 7) * 4;
      sw[q] = *reinterpret_cast<const float4*>(&W[(size_t)e * KDIM + kb + kq]);
    }
  }
  for (int s = 0; s < 8; ++s) {
    __syncthreads();
#pragma unroll
    for (int q = 0; q < 4; ++q) {
      const int li = tid + q * 256, row = li >> 3, kq = (li & 7) * 4;
      *reinterpret_cast<float4*>(&xs[row][kq]) = sx[q];
    }
#pragma unroll
    for (int q = 0; q < 2; ++q) {
      const int li = tid + q * 256, e = li >> 3, kq = (li & 7) * 4;
      wt[kq][e] = sw[q].x; wt[kq + 1][e] = sw[q].y;
      wt[kq + 2][e] = sw[q].z; wt[kq + 3][e] = sw[q].w;
    }
    if (s < 7) {
      const int kb = kc * KCHUNK + (s + 1) * 32;
#pragma unroll
      for (int q = 0; q < 4; ++q) {
        const int li = tid + q * 256, row = li >> 3, kq = (li & 7) * 4;
        sx[q] = *reinterpret_cast<const float4*>(&x[(size_t)(r0 + row) * KDIM + kb + kq]);
      }
#pragma unroll
      for (int q = 0; q < 2; ++q) {
        const int li = tid + q * 256, e = li >> 3, kq = (li & 7) * 4;
        sw[q] = *reinterpret_cast<const float4*>(&W[(size_t)e * KDIM + kb + kq]);
      }
    }
    __syncthreads();
#pragma unroll
    for (int k4 = 0; k4 < 8; ++k4) {
      float4 wb[4];
#pragma unroll
      for (int j = 0; j < 4; ++j)
        wb[j] = *reinterpret_cast<const float4*>(&wt[k4 * 4 + j][er * 4]);
#pragma unroll
      for (int i = 0; i < 8; ++i) {
        const float4 xv = *reinterpret_cast<const float4*>(&xs[rg + 16 * i][k4 * 4]);
        acc[i][0] = fmaf(xv.w, wb[3].x, fmaf(xv.z, wb[2].x, fmaf(xv.y, wb[1].x, fmaf(xv.x, wb[0].x, acc[i][0]))));
        acc[i][1] = fmaf(xv.w, wb[3].y, fmaf(xv.z, wb[2].y, fmaf(xv.y, wb[1].y, fmaf(xv.x, wb[0].y, acc[i][1]))));
        acc[i][2] = fmaf(xv.w, wb[3].z, fmaf(xv.z, wb[2].z, fmaf(xv.y, wb[1].z, fmaf(xv.x, wb[0].z, acc[i][2]))));
        acc[i][3] = fmaf(xv.w, wb[3].w, fmaf(xv.z, wb[2].w, fmaf(xv.y, wb[1].w, fmaf(xv.x, wb[0].w, acc[i][3]))));
      }
    }
  }
#pragma unroll
  for (int i = 0; i < 8; ++i) {
    float4 v; v.x = acc[i][0]; v.y = acc[i][1]; v.z = acc[i][2]; v.w = acc[i][3];
    *reinterpret_cast<float4*>(
        &part[((size_t)kc * T_TOK + r0 + rg + 16 * i) * NE + er * 4]) = v;
  }
}

// ---- fillsoft: blocks 0..127 = softmax (R7 k_soft verbatim), rest = fill ----
__global__ __launch_bounds__(256)
void k_fillsoft(const float* __restrict__ part, float2* __restrict__ g12,
                int* __restrict__ idxs, float* __restrict__ me_part,
                float* __restrict__ out,
                int s1lo, int s1hi, int s2lo, int s2hi, int fillLast) {
  __shared__ float lg[64][33];
  const int tid = threadIdx.x;
  if (blockIdx.x >= 128) {  // ---------- static fill role ----------
    const int fb = (int)blockIdx.x - 128;
    float4* p4 = reinterpret_cast<float4*>(out);
    const float4 z4 = make_float4(0.f, 0.f, 0.f, 0.f);
    const int start = fb * 5120;
#pragma unroll
    for (int j = 0; j < 20; ++j) {
      const int i4 = start + tid + j * 256;
      if (i4 >= s1lo && i4 < s1hi) continue;
      if (i4 >= s2lo && i4 < s2hi) continue;
      p4[i4] = z4;
    }
    if (fillLast && fb == NFB - 1 && tid == 255) out[OUT_ELEMS - 1] = 0.f;
    return;
  }
  // ---------- softmax role (R7 k_soft verbatim, tid<64 active) ----------
  if (tid < 64) {
    const int R = (int)blockIdx.x * 64 + tid;
    const int t = R >> 1;
    const int p = R & 1;
    float v[32];
    const float* pr = part + (size_t)t * NE + p * EE;
#pragma unroll
    for (int e = 0; e < 32; e += 4) {
      const float4 s = *reinterpret_cast<const float4*>(pr + e);
      v[e] = s.x; v[e + 1] = s.y; v[e + 2] = s.z; v[e + 3] = s.w;
    }
    for (int kc = 1; kc < NKC; ++kc) {
      const float* prk = pr + (size_t)kc * T_TOK * NE;
#pragma unroll
      for (int e = 0; e < 32; e += 4) {
        const float4 s = *reinterpret_cast<const float4*>(prk + e);
        v[e] += s.x; v[e + 1] += s.y; v[e + 2] += s.z; v[e + 3] += s.w;
      }
    }
    float m = v[0];
#pragma unroll
    for (int e = 1; e < 32; ++e) m = fmaxf(m, v[e]);
    float sum = 0.f;
#pragma unroll
    for (int e = 0; e < 32; ++e) { v[e] = expf(v[e] - m); sum += v[e]; }
    const float inv = 1.0f / sum;
#pragma unroll
    for (int e = 0; e < 32; ++e) v[e] *= inv;
    float g1 = -1.f; int i1 = 0;
#pragma unroll
    for (int e = 0; e < 32; ++e) if (v[e] > g1) { g1 = v[e]; i1 = e; }  // first-max
    float g2 = -1.f; int i2 = 0;
#pragma unroll
    for (int e = 0; e < 32; ++e) if (e != i1 && v[e] > g2) { g2 = v[e]; i2 = e; }
    g12[R] = make_float2(g1, g2);
    idxs[R] = i1 | (i2 << 8);
#pragma unroll
    for (int e = 0; e < 32; ++e) lg[tid][e] = v[e];
  }
  __syncthreads();
  if (tid < 64) {
    const int pp = tid >> 5, ee = tid & 31;
    float s = 0.f;
    for (int rr = pp; rr < 64; rr += 2) s += lg[rr][ee];
    me_part[(int)blockIdx.x * 64 + tid] = s;
  }
}

// ------- scan (R6-proven) + inline point-fixes + l_aux (R10-proven) ----------
__global__ __launch_bounds__(1024) void k_scan2(const int* __restrict__ idxs,
                                                const float2* __restrict__ g12,
                                                const float* __restrict__ me_part,
                                                int2* __restrict__ fl,
                                                float2* __restrict__ wvp,
                                                float* __restrict__ out,
                                                int rlimit) {
  __shared__ int grp[NP][64][32];
  __shared__ int tot[NP][32];
  __shared__ unsigned short tk1[NP][T_TOK];
  __shared__ unsigned short tk2[NP][T_TOK];
  __shared__ float red[64];
  const int tid = threadIdx.x;
  const int wvi = tid >> 6;
  const int p = wvi >> 3;
  const int wg = wvi & 7;
  const int l = tid & 63;
  const unsigned long long lmask = (1ull << l) - 1ull;
  for (int gi = 0; gi < 8; ++gi) {
    const int g = wg * 8 + gi;
    const int t = g * 64 + l;
    const int e1 = idxs[t * 2 + p] & 255;
    if (l < 32) grp[p][g][l] = 0;
    unsigned long long m = ~0ull;
#pragma unroll
    for (int b = 0; b < 5; ++b) {
      const unsigned long long bm = __ballot((e1 >> b) & 1);
      m &= ((e1 >> b) & 1) ? bm : ~bm;
    }
    const int rank = (int)__popcll(m & lmask);
    if (rank == 0) grp[p][g][e1] = (int)__popcll(m);
    tk1[p][t] = (unsigned short)(rank | (e1 << 6));
  }
  __syncthreads();
  if (tid < 64) {
    const int pp = tid >> 5, ee = tid & 31;
    int s = 0;
    for (int g = 0; g < 64; ++g) { int vv = grp[pp][g][ee]; grp[pp][g][ee] = s; s += vv; }
    tot[pp][ee] = s;
  }
  __syncthreads();
  for (int gi = 0; gi < 8; ++gi) {
    const int g = wg * 8 + gi;
    const int t = g * 64 + l;
    const int vv = tk1[p][t];
    tk1[p][t] = (unsigned short)(grp[p][g][vv >> 6] + (vv & 63));
  }
  if (tid < 64) {
    float s = 0.f;
    for (int b = 0; b < 128; ++b) s += me_part[b * 64 + tid];
    red[tid] = s * (float)tot[tid >> 5][tid & 31];
  }
  __syncthreads();
  if (tid == 0) {
    float s = 0.f;
    for (int i = 0; i < 64; ++i) s += red[i];
    out[0] = s / (64.0f * 4096.0f * 4096.0f);
  }
  for (int gi = 0; gi < 8; ++gi) {
    const int g = wg * 8 + gi;
    const int t = g * 64 + l;
    const int ii = idxs[t * 2 + p];
    const int e2 = (tk1[p][t] < CAP) ? (ii >> 8) : (ii & 255);
    if (l < 32) grp[p][g][l] = 0;
    unsigned long long m = ~0ull;
#pragma unroll
    for (int b = 0; b < 5; ++b) {
      const unsigned long long bm = __ballot((e2 >> b) & 1);
      m &= ((e2 >> b) & 1) ? bm : ~bm;
    }
    const int rank = (int)__popcll(m & lmask);
    if (rank == 0) grp[p][g][e2] = (int)__popcll(m);
    tk2[p][t] = (unsigned short)(rank | (e2 << 6));
  }
  __syncthreads();
  if (tid < 64) {
    const int pp = tid >> 5, ee = tid & 31;
    int s = min(tot[pp][ee], CAP);
    for (int g = 0; g < 64; ++g) { int vv = grp[pp][g][ee]; grp[pp][g][ee] = s; s += vv; }
  }
  __syncthreads();
  for (int gi = 0; gi < 8; ++gi) {
    const int g = wg * 8 + gi;
    const int t = g * 64 + l;
    const int R = t * 2 + p;
    const int ii = idxs[R];
    const int e1 = ii & 255;
    const int loc1v = tk1[p][t];
    const bool kept1 = loc1v < CAP;
    const int v2 = tk2[p][t];
    const int rank2 = v2 & 63, e2 = v2 >> 6;
    const int loc2 = grp[p][g][e2] + rank2;
    const bool kept2 = loc2 < CAP;
    const float2 gg = g12[R];
    const float gs1 = kept1 ? gg.x : 0.f;
    const float g2v = kept1 ? gg.y : gg.x;
    const float gs2 = kept2 ? g2v : 0.f;
    const float den = fmaxf(gs1 + gs2, 1.1920929e-07f);  // FLT_EPSILON
    const int f1 = kept1 ? e1 * CAP + loc1v : -1;
    const int f2 = kept2 ? e2 * CAP + loc2 : -1;
    const float w1 = gs1 / den, w2 = gs2 / den;
    fl[R] = make_int2(f1, f2);
    wvp[R] = make_float2(w1, w2);
    float* oc = out + 1 + (size_t)R * 5120;  // zeros already down
    if (f1 >= 0) oc[f1] = w1;
    if (f2 >= 0) oc[f2] = w2;
    if (R < rlimit) {
      float* od = out + 1 + COMB_ELEMS + (size_t)R * 5120;
      if (f1 >= 0) od[f1] = 1.0f;
      if (f2 >= 0) od[f2] = 1.0f;
    }
  }
}

// pathB: zero the part window (tail of dispatch) after soft consumed it
__global__ __launch_bounds__(256) void k_tailB(float* __restrict__ out) {
  float4* p4 = reinterpret_cast<float4*>(out);
  const float4 z4 = make_float4(0.f, 0.f, 0.f, 0.f);
  const int base = 20447232 + (int)blockIdx.x * 4096 + (int)threadIdx.x;
#pragma unroll
  for (int j = 0; j < 16; ++j) p4[base + j * 256] = z4;
  if (blockIdx.x == 0 && threadIdx.x == 0) out[OUT_ELEMS - 1] = 0.f;
}

// pathC: zero the part window at combine front (after soft consumed it)
__global__ __launch_bounds__(256) void k_fill2C(float* __restrict__ out) {
  float4* p4 = reinterpret_cast<float4*>(out + 4);
  const float4 z4 = make_float4(0.f, 0.f, 0.f, 0.f);
  const int base = (int)blockIdx.x * 2048 + (int)threadIdx.x;
#pragma unroll
  for (int j = 0; j < 8; ++j) p4[base + j * 256] = z4;
}

// pathC: zero dispatch-tail scratch window + its rows' fixes (from fl)
__global__ __launch_bounds__(1024) void k_tailC(const int2* __restrict__ fl,
                                                float* __restrict__ out,
                                                int nfullB) {
  __shared__ int2 sfl[16];
  const int tid = threadIdx.x;
  const int rstart = nfullB * 2;
  const int nr = 8192 - rstart;  // <= 16
  if (tid < nr) sfl[tid] = fl[rstart + tid];
  __syncthreads();
  const size_t base = 1 + COMB_ELEMS + (size_t)rstart * 5120;
  const int cnt = nr * 5120;
  const int nx4 = (cnt - 4) >> 2;
  float4* p4 = (float4*)(out + base + 3);
  const float4 z4 = make_float4(0.f, 0.f, 0.f, 0.f);
  for (int idx = tid; idx < nx4; idx += 1024) p4[idx] = z4;
  if (tid < 3) out[base + tid] = 0.f;
  if (tid == 3) out[base + cnt - 1] = 0.f;
  __syncthreads();
  if (tid < 2 * nr) {
    const int rr = rstart + (tid >> 1);
    const int2 f = sfl[tid >> 1];
    const int pos = (tid & 1) ? f.y : f.x;
    if (pos >= 0) out[1 + COMB_ELEMS + (size_t)rr * 5120 + pos] = 1.0f;
  }
}

extern "C" void kernel_launch(void* const* d_in, const int* in_sizes, int n_in,
                              void* d_out, int out_size, void* d_ws, size_t ws_size,
                              hipStream_t stream) {
  const float* x = (const float*)d_in[0];
  const float* W = (const float*)d_in[1];
  float* out = (float*)d_out;

  const bool pathA = ws_size >= (SMALLF + PARTF) * sizeof(float);
  const bool pathB = !pathA && ws_size >= SMALLF * sizeof(float);

  float* small;
  float* part;
  int s1lo = 0, s1hi = 0, s2lo = 0, s2hi = 0, fillLast = 1;
  int rlimit = 8192, nfullB = 4096;
  if (pathA) {
    small = (float*)d_ws;
    part = small + SMALLF;
  } else if (pathB) {
    small = (float*)d_ws;
    part = out + PB_F;
    s1lo = PB_F / 4; s1hi = TOT4;           // part window in dispatch tail
    fillLast = 0;                            // tailB handles last elem
  } else {
    const size_t tb = (OUT_ELEMS - SMALLF) & ~(size_t)3;  // 83820544
    small = out + tb;
    part = out + 4;
    s1lo = 1; s1hi = 1 + (int)(PARTF / 4);   // part window at combine front
    s2lo = (int)(tb / 4); s2hi = TOT4;       // scratch window at tail
    fillLast = 0;
    nfullB = (int)((tb - 1 - COMB_ELEMS) / 10240);  // 4089
    rlimit = nfullB * 2;
  }
  float2* g12 = (float2*)small;
  int* idxs = (int*)(small + 16384);
  float* me_part = small + 24576;
  int2* fl = (int2*)(small + 32768);
  float2* wvp = (float2*)(small + 49152);

  hipLaunchKernelGGL(k_gemm, dim3(256), dim3(256), 0, stream, x, W, part);
  hipLaunchKernelGGL(k_fillsoft, dim3(128 + NFB), dim3(256), 0, stream,
                     part, g12, idxs, me_part, out, s1lo, s1hi, s2lo, s2hi, fillLast);
  if (pathB)
    hipLaunchKernelGGL(k_tailB, dim3(128), dim3(256), 0, stream, out);
  if (!pathA && !pathB)
    hipLaunchKernelGGL(k_fill2C, dim3(256), dim3(256), 0, stream, out);
  hipLaunchKernelGGL(k_scan2, dim3(1), dim3(1024), 0, stream,
                     idxs, g12, me_part, fl, wvp, out, rlimit);
  if (!pathA && !pathB)
    hipLaunchKernelGGL(k_tailC, dim3(1), dim3(1024), 0, stream, fl, out, nfullB);
}

// Round 12
// 123.013 us; speedup vs baseline: 2.8787x; 1.0123x over previous
//
#include <hip/hip_runtime.h>
#include <cstdint>

#define T_TOK 4096
#define KDIM 2048
#define NE 64
#define NP 2
#define EE 32
#define CAP 160
#define NKC 8
#define KCHUNK 256
#define BLKR 128
#define COMB_ELEMS 41943040ull /* 8192 * 5120 */
#define OUT_ELEMS 83886081ull  /* 1 + 2*COMB */
#define PARTF 2097152ull
#define TOT4 20971520
#define SMALLF 65544           /* g12|idxs|me|fl|wvp|laux */
#define PB_F 81788928          /* pathB part offset (16B-aligned float idx) */

// ---------------- GEMM standalone (R6/R7-proven, verbatim math) --------------
__global__ __launch_bounds__(256) void k_gemm(const float* __restrict__ x,
                                              const float* __restrict__ W,
                                              float* __restrict__ part) {
  __shared__ float xs[BLKR][36];
  __shared__ float wt[32][68];
  const int tid = threadIdx.x;
  const int rb = (int)blockIdx.x & 31;
  const int kc = (int)blockIdx.x >> 5;
  const int r0 = rb * BLKR;
  const int er = tid & 15;
  const int rg = tid >> 4;
  float acc[8][4];
#pragma unroll
  for (int i = 0; i < 8; ++i)
#pragma unroll
    for (int c = 0; c < 4; ++c) acc[i][c] = 0.f;
  float4 sx[4], sw[2];
  {
    const int kb = kc * KCHUNK;
#pragma unroll
    for (int q = 0; q < 4; ++q) {
      const int li = tid + q * 256, row = li >> 3, kq = (li & 7) * 4;
      sx[q] = *reinterpret_cast<const float4*>(&x[(size_t)(r0 + row) * KDIM + kb + kq]);
    }
#pragma unroll
    for (int q = 0; q < 2; ++q) {
      const int li = tid + q * 256, e = li >> 3, kq = (li & 7) * 4;
      sw[q] = *reinterpret_cast<const float4*>(&W[(size_t)e * KDIM + kb + kq]);
    }
  }
  for (int s = 0; s < 8; ++s) {
    __syncthreads();
#pragma unroll
    for (int q = 0; q < 4; ++q) {
      const int li = tid + q * 256, row = li >> 3, kq = (li & 7) * 4;
      *reinterpret_cast<float4*>(&xs[row][kq]) = sx[q];
    }
#pragma unroll
    for (int q = 0; q < 2; ++q) {
      const int li = tid + q * 256, e = li >> 3, kq = (li & 7) * 4;
      wt[kq][e] = sw[q].x; wt[kq + 1][e] = sw[q].y;
      wt[kq + 2][e] = sw[q].z; wt[kq + 3][e] = sw[q].w;
    }
    if (s < 7) {
      const int kb = kc * KCHUNK + (s + 1) * 32;
#pragma unroll
      for (int q = 0; q < 4; ++q) {
        const int li = tid + q * 256, row = li >> 3, kq = (li & 7) * 4;
        sx[q] = *reinterpret_cast<const float4*>(&x[(size_t)(r0 + row) * KDIM + kb + kq]);
      }
#pragma unroll
      for (int q = 0; q < 2; ++q) {
        const int li = tid + q * 256, e = li >> 3, kq = (li & 7) * 4;
        sw[q] = *reinterpret_cast<const float4*>(&W[(size_t)e * KDIM + kb + kq]);
      }
    }
    __syncthreads();
#pragma unroll
    for (int k4 = 0; k4 < 8; ++k4) {
      float4 wb[4];
#pragma unroll
      for (int j = 0; j < 4; ++j)
        wb[j] = *reinterpret_cast<const float4*>(&wt[k4 * 4 + j][er * 4]);
#pragma unroll
      for (int i = 0; i < 8; ++i) {
        const float4 xv = *reinterpret_cast<const float4*>(&xs[rg + 16 * i][k4 * 4]);
        acc[i][0] = fmaf(xv.w, wb[3].x, fmaf(xv.z, wb[2].x, fmaf(xv.y, wb[1].x, fmaf(xv.x, wb[0].x, acc[i][0]))));
        acc[i][1] = fmaf(xv.w, wb[3].y, fmaf(xv.z, wb[2].y, fmaf(xv.y, wb[1].y, fmaf(xv.x, wb[0].y, acc[i][1]))));
        acc[i][2] = fmaf(xv.w, wb[3].z, fmaf(xv.z, wb[2].z, fmaf(xv.y, wb[1].z, fmaf(xv.x, wb[0].z, acc[i][2]))));
        acc[i][3] = fmaf(xv.w, wb[3].w, fmaf(xv.z, wb[2].w, fmaf(xv.y, wb[1].w, fmaf(xv.x, wb[0].w, acc[i][3]))));
      }
    }
  }
#pragma unroll
  for (int i = 0; i < 8; ++i) {
    float4 v; v.x = acc[i][0]; v.y = acc[i][1]; v.z = acc[i][2]; v.w = acc[i][3];
    *reinterpret_cast<float4*>(
        &part[((size_t)kc * T_TOK + r0 + rg + 16 * i) * NE + er * 4]) = v;
  }
}

// ------------- softmax + top2 + me partials (R7-proven verbatim) -------------
__global__ __launch_bounds__(64) void k_soft(const float* __restrict__ part,
                                             float2* __restrict__ g12,
                                             int* __restrict__ idxs,
                                             float* __restrict__ me_part) {
  __shared__ float lg[64][33];
  const int tid = threadIdx.x;
  const int R = blockIdx.x * 64 + tid;
  const int t = R >> 1;
  const int p = R & 1;
  float v[32];
  const float* pr = part + (size_t)t * NE + p * EE;
#pragma unroll
  for (int e = 0; e < 32; e += 4) {
    float4 s = *reinterpret_cast<const float4*>(pr + e);
    v[e] = s.x; v[e + 1] = s.y; v[e + 2] = s.z; v[e + 3] = s.w;
  }
  for (int kc = 1; kc < NKC; ++kc) {
    const float* prk = pr + (size_t)kc * T_TOK * NE;
#pragma unroll
    for (int e = 0; e < 32; e += 4) {
      float4 s = *reinterpret_cast<const float4*>(prk + e);
      v[e] += s.x; v[e + 1] += s.y; v[e + 2] += s.z; v[e + 3] += s.w;
    }
  }
  float m = v[0];
#pragma unroll
  for (int e = 1; e < 32; ++e) m = fmaxf(m, v[e]);
  float sum = 0.f;
#pragma unroll
  for (int e = 0; e < 32; ++e) { v[e] = expf(v[e] - m); sum += v[e]; }
  const float inv = 1.0f / sum;
#pragma unroll
  for (int e = 0; e < 32; ++e) v[e] *= inv;
  float g1 = -1.f; int i1 = 0;
#pragma unroll
  for (int e = 0; e < 32; ++e) if (v[e] > g1) { g1 = v[e]; i1 = e; }  // first-max
  float g2 = -1.f; int i2 = 0;
#pragma unroll
  for (int e = 0; e < 32; ++e) if (e != i1 && v[e] > g2) { g2 = v[e]; i2 = e; }
  g12[R] = make_float2(g1, g2);
  idxs[R] = i1 | (i2 << 8);
#pragma unroll
  for (int e = 0; e < 32; ++e) lg[tid][e] = v[e];
  __syncthreads();
  {
    const int pp = tid >> 5, ee = tid & 31;
    float s = 0.f;
    for (int rr = pp; rr < 64; rr += 2) s += lg[rr][ee];
    me_part[blockIdx.x * 64 + tid] = s;
  }
}

// ------- scans (R10-proven logic); results to scratch ONLY -------------------
__global__ __launch_bounds__(1024) void k_scan3(const int* __restrict__ idxs,
                                                const float2* __restrict__ g12,
                                                const float* __restrict__ me_part,
                                                int2* __restrict__ fl,
                                                float2* __restrict__ wvp,
                                                float* __restrict__ laux) {
  __shared__ int grp[NP][64][32];
  __shared__ int tot[NP][32];
  __shared__ unsigned short tk1[NP][T_TOK];
  __shared__ unsigned short tk2[NP][T_TOK];
  __shared__ float red[64];
  const int tid = threadIdx.x;
  const int wvi = tid >> 6;
  const int p = wvi >> 3;
  const int wg = wvi & 7;
  const int l = tid & 63;
  const unsigned long long lmask = (1ull << l) - 1ull;
  for (int gi = 0; gi < 8; ++gi) {
    const int g = wg * 8 + gi;
    const int t = g * 64 + l;
    const int e1 = idxs[t * 2 + p] & 255;
    if (l < 32) grp[p][g][l] = 0;
    unsigned long long m = ~0ull;
#pragma unroll
    for (int b = 0; b < 5; ++b) {
      const unsigned long long bm = __ballot((e1 >> b) & 1);
      m &= ((e1 >> b) & 1) ? bm : ~bm;
    }
    const int rank = (int)__popcll(m & lmask);
    if (rank == 0) grp[p][g][e1] = (int)__popcll(m);
    tk1[p][t] = (unsigned short)(rank | (e1 << 6));
  }
  __syncthreads();
  if (tid < 64) {
    const int pp = tid >> 5, ee = tid & 31;
    int s = 0;
    for (int g = 0; g < 64; ++g) { int vv = grp[pp][g][ee]; grp[pp][g][ee] = s; s += vv; }
    tot[pp][ee] = s;
  }
  __syncthreads();
  for (int gi = 0; gi < 8; ++gi) {
    const int g = wg * 8 + gi;
    const int t = g * 64 + l;
    const int vv = tk1[p][t];
    tk1[p][t] = (unsigned short)(grp[p][g][vv >> 6] + (vv & 63));
  }
  if (tid < 64) {
    float s = 0.f;
    for (int b = 0; b < 128; ++b) s += me_part[b * 64 + tid];
    red[tid] = s * (float)tot[tid >> 5][tid & 31];
  }
  __syncthreads();
  if (tid == 0) {
    float s = 0.f;
    for (int i = 0; i < 64; ++i) s += red[i];
    laux[0] = s / (64.0f * 4096.0f * 4096.0f);
  }
  for (int gi = 0; gi < 8; ++gi) {
    const int g = wg * 8 + gi;
    const int t = g * 64 + l;
    const int ii = idxs[t * 2 + p];
    const int e2 = (tk1[p][t] < CAP) ? (ii >> 8) : (ii & 255);
    if (l < 32) grp[p][g][l] = 0;
    unsigned long long m = ~0ull;
#pragma unroll
    for (int b = 0; b < 5; ++b) {
      const unsigned long long bm = __ballot((e2 >> b) & 1);
      m &= ((e2 >> b) & 1) ? bm : ~bm;
    }
    const int rank = (int)__popcll(m & lmask);
    if (rank == 0) grp[p][g][e2] = (int)__popcll(m);
    tk2[p][t] = (unsigned short)(rank | (e2 << 6));
  }
  __syncthreads();
  if (tid < 64) {
    const int pp = tid >> 5, ee = tid & 31;
    int s = min(tot[pp][ee], CAP);
    for (int g = 0; g < 64; ++g) { int vv = grp[pp][g][ee]; grp[pp][g][ee] = s; s += vv; }
  }
  __syncthreads();
  for (int gi = 0; gi < 8; ++gi) {
    const int g = wg * 8 + gi;
    const int t = g * 64 + l;
    const int R = t * 2 + p;
    const int ii = idxs[R];
    const int e1 = ii & 255;
    const int loc1v = tk1[p][t];
    const bool kept1 = loc1v < CAP;
    const int v2 = tk2[p][t];
    const int rank2 = v2 & 63, e2 = v2 >> 6;
    const int loc2 = grp[p][g][e2] + rank2;
    const bool kept2 = loc2 < CAP;
    const float2 gg = g12[R];
    const float gs1 = kept1 ? gg.x : 0.f;
    const float g2v = kept1 ? gg.y : gg.x;
    const float gs2 = kept2 ? g2v : 0.f;
    const float den = fmaxf(gs1 + gs2, 1.1920929e-07f);  // FLT_EPSILON
    fl[R] = make_int2(kept1 ? e1 * CAP + loc1v : -1, kept2 ? e2 * CAP + loc2 : -1);
    wvp[R] = make_float2(gs1 / den, gs2 / den);
  }
}

// ---- fill-last: zero spans + <=4 point fixes per block + l_aux --------------
__global__ __launch_bounds__(256)
void k_fillfix(const int2* __restrict__ fl, const float2* __restrict__ wvp,
               const float* __restrict__ laux, float* __restrict__ out,
               int s2flo, int s2fhi, int rlimit) {
  const int b = (int)blockIdx.x;       // 0..4095 combine, 4096..8191 dispatch
  const int tid = threadIdx.x;
  const int region = b >> 12;
  const int bd = b & 4095;             // rows 2bd, 2bd+1
  int fpos = -1; float fval = 0.f; size_t faddr = 0;
  if (tid < 4) {
    const int rr = 2 * bd + (tid >> 1);
    const int2 f = fl[rr];
    const float2 w = wvp[rr];
    const int which = tid & 1;
    fpos = which ? f.y : f.x;
    fval = region ? 1.0f : (which ? w.y : w.x);
    faddr = 1ull + (region ? COMB_ELEMS : 0ull) + (size_t)rr * 5120 + (size_t)(fpos < 0 ? 0 : fpos);
    if (region && rr >= rlimit) fpos = -1;  // deferred to tailC (pathC)
  }
  const size_t base = 1 + (region ? COMB_ELEMS : 0ull) + (size_t)bd * 10240;
  float4* p4 = (float4*)(out + base + 3);  // 16B-aligned
  const float4 z4 = make_float4(0.f, 0.f, 0.f, 0.f);
  const long long b4base = (long long)((base + 3) >> 2);
#pragma unroll
  for (int j = 0; j < 10; ++j) {
    const int idx = tid + j * 256;
    if (idx < 2559) {
      const long long a4 = b4base + idx;
      if (a4 >= s2flo && a4 < s2fhi) continue;  // pathC scratch window
      p4[idx] = z4;
    }
  }
  if (tid < 3) { const size_t f = base + tid; if (!((long long)(f >> 2) >= s2flo && (long long)(f >> 2) < s2fhi)) out[f] = 0.f; }
  if (tid == 3) { const size_t f = base + 10239; if (!((long long)(f >> 2) >= s2flo && (long long)(f >> 2) < s2fhi)) out[f] = 0.f; }
  if (b == 0 && tid == 4) out[0] = laux[0];
  __syncthreads();
  if (tid < 4 && fpos >= 0) out[faddr] = fval;
}

// pathC: zero dispatch-tail scratch window rows + their fixes (from fl in LDS)
__global__ __launch_bounds__(1024) void k_tailC(const int2* __restrict__ fl,
                                                float* __restrict__ out,
                                                int rstart) {
  __shared__ int2 sfl[16];
  const int tid = threadIdx.x;
  const int nr = 8192 - rstart;  // <= 16
  if (tid < nr) sfl[tid] = fl[rstart + tid];
  __syncthreads();
  const size_t base = 1 + COMB_ELEMS + (size_t)rstart * 5120;  // == 1 mod 4
  const int cnt = nr * 5120;
  const int nx4 = (cnt - 4) >> 2;
  float4* p4 = (float4*)(out + base + 3);
  const float4 z4 = make_float4(0.f, 0.f, 0.f, 0.f);
  for (int idx = tid; idx < nx4; idx += 1024) p4[idx] = z4;
  if (tid < 3) out[base + tid] = 0.f;
  if (tid == 3) out[base + cnt - 1] = 0.f;
  __syncthreads();
  if (tid < 2 * nr) {
    const int rr = rstart + (tid >> 1);
    const int2 f = sfl[tid >> 1];
    const int pos = (tid & 1) ? f.y : f.x;
    if (pos >= 0) out[1 + COMB_ELEMS + (size_t)rr * 5120 + pos] = 1.0f;
  }
}

extern "C" void kernel_launch(void* const* d_in, const int* in_sizes, int n_in,
                              void* d_out, int out_size, void* d_ws, size_t ws_size,
                              hipStream_t stream) {
  const float* x = (const float*)d_in[0];
  const float* W = (const float*)d_in[1];
  float* out = (float*)d_out;

  const bool pathA = ws_size >= (SMALLF + PARTF) * sizeof(float);
  const bool pathB = !pathA && ws_size >= SMALLF * sizeof(float);

  float* small;
  float* part;
  int s2flo = 0, s2fhi = 0, rlimit = 8192, rstart = 8192;
  if (pathA) {
    small = (float*)d_ws;
    part = small + SMALLF;
  } else if (pathB) {
    small = (float*)d_ws;
    part = out + PB_F;  // dispatch tail; consumed by soft, then zeroed by fill
  } else {
    const size_t tb = (OUT_ELEMS - SMALLF) & ~(size_t)3;  // 83820536
    small = out + tb;
    part = out + 4;
    s2flo = (int)(tb >> 2); s2fhi = TOT4;  // f4 window over scratch
    rstart = (int)((tb - 1 - COMB_ELEMS) / 5120);  // 8179: first row overlapping
    rlimit = rstart;
  }
  float2* g12 = (float2*)small;
  int* idxs = (int*)(small + 16384);
  float* me_part = small + 24576;
  int2* fl = (int2*)(small + 32768);
  float2* wvp = (float2*)(small + 49152);
  float* laux = small + 65536;

  hipLaunchKernelGGL(k_gemm, dim3(256), dim3(256), 0, stream, x, W, part);
  hipLaunchKernelGGL(k_soft, dim3(128), dim3(64), 0, stream, part, g12, idxs, me_part);
  hipLaunchKernelGGL(k_scan3, dim3(1), dim3(1024), 0, stream,
                     idxs, g12, me_part, fl, wvp, laux);
  hipLaunchKernelGGL(k_fillfix, dim3(8192), dim3(256), 0, stream,
                     fl, wvp, laux, out, s2flo, s2fhi, rlimit);
  if (rstart < 8192)
    hipLaunchKernelGGL(k_tailC, dim3(1), dim3(1024), 0, stream, fl, out, rstart);
}

// Round 15
// 114.646 us; speedup vs baseline: 3.0888x; 1.0730x over previous
//
#include <hip/hip_runtime.h>
#include <cstdint>

#define T_TOK 4096
#define KDIM 2048
#define NE 64
#define NP 2
#define EE 32
#define CAP 160
#define NKC 8
#define KCHUNK 256
#define COMB_ELEMS 41943040ull /* 8192 * 5120 */
#define OUT_ELEMS 83886081ull  /* 1 + 2*COMB */
#define PARTF 2097152ull
#define TOT4 20971520
#define SMALLF 65536           /* g12 16384 | idxs 8192 | me 8192 | fl 16384 | wvp 16384 */
#define PB_F 81788928          /* pathB part offset (16B-aligned float idx) */

// ---- fused: blocks 0..255 gemm (512t, 128r x 64e x 256k, 2 waves/SIMD);
// ---- blocks 256..2303 static zero-fill (10240 f4 each) -----------------
__global__ __launch_bounds__(512)
void k_fused(const float* __restrict__ x, const float* __restrict__ W,
             float* __restrict__ part, float* __restrict__ out,
             int s1lo, int s1hi, int s2lo, int s2hi, int fillLast) {
  __shared__ float xs[128][36];
  __shared__ float wt[32][68];
  const int tid = threadIdx.x;
  if (blockIdx.x >= 256) {  // ---------- fill role ----------
    const int fb = (int)blockIdx.x - 256;
    float4* p4 = reinterpret_cast<float4*>(out);
    const float4 z4 = make_float4(0.f, 0.f, 0.f, 0.f);
    const int start = fb * 10240;
#pragma unroll
    for (int j = 0; j < 20; ++j) {
      const int i4 = start + tid + j * 512;
      if (i4 >= s1lo && i4 < s1hi) continue;
      if (i4 >= s2lo && i4 < s2hi) continue;
      p4[i4] = z4;
    }
    if (fillLast && fb == 2047 && tid == 511) out[OUT_ELEMS - 1] = 0.f;
    return;
  }
  // ---------- gemm role: per-thread 4r x 4e, k-chain identical to R6-R12 ----
  const int rb = (int)blockIdx.x & 31;
  const int kc = (int)blockIdx.x >> 5;
  const int r0 = rb * 128;
  const int er = tid & 15;   // experts er*4..+3
  const int rg = tid >> 4;   // 0..31; rows rg + 32*i, i=0..3
  float acc[4][4];
#pragma unroll
  for (int i = 0; i < 4; ++i)
#pragma unroll
    for (int c = 0; c < 4; ++c) acc[i][c] = 0.f;
  float4 sx[2], sw1;
  {
    const int kb = kc * KCHUNK;
#pragma unroll
    for (int q = 0; q < 2; ++q) {
      const int li = tid + q * 512, row = li >> 3, kq = (li & 7) * 4;
      sx[q] = *reinterpret_cast<const float4*>(&x[(size_t)(r0 + row) * KDIM + kb + kq]);
    }
    { const int e = tid >> 3, kq = (tid & 7) * 4;
      sw1 = *reinterpret_cast<const float4*>(&W[(size_t)e * KDIM + kb + kq]); }
  }
  for (int s = 0; s < 8; ++s) {
    __syncthreads();
#pragma unroll
    for (int q = 0; q < 2; ++q) {
      const int li = tid + q * 512, row = li >> 3, kq = (li & 7) * 4;
      *reinterpret_cast<float4*>(&xs[row][kq]) = sx[q];
    }
    { const int e = tid >> 3, kq = (tid & 7) * 4;
      wt[kq][e] = sw1.x; wt[kq + 1][e] = sw1.y;
      wt[kq + 2][e] = sw1.z; wt[kq + 3][e] = sw1.w; }
    if (s < 7) {
      const int kb = kc * KCHUNK + (s + 1) * 32;
#pragma unroll
      for (int q = 0; q < 2; ++q) {
        const int li = tid + q * 512, row = li >> 3, kq = (li & 7) * 4;
        sx[q] = *reinterpret_cast<const float4*>(&x[(size_t)(r0 + row) * KDIM + kb + kq]);
      }
      { const int e = tid >> 3, kq = (tid & 7) * 4;
        sw1 = *reinterpret_cast<const float4*>(&W[(size_t)e * KDIM + kb + kq]); }
    }
    __syncthreads();
#pragma unroll
    for (int k4 = 0; k4 < 8; ++k4) {
      float4 wb[4];
#pragma unroll
      for (int j = 0; j < 4; ++j)
        wb[j] = *reinterpret_cast<const float4*>(&wt[k4 * 4 + j][er * 4]);
#pragma unroll
      for (int i = 0; i < 4; ++i) {
        const float4 xv = *reinterpret_cast<const float4*>(&xs[rg + 32 * i][k4 * 4]);
        // k-ascending nested fmaf: bitwise-identical per-output chain
        acc[i][0] = fmaf(xv.w, wb[3].x, fmaf(xv.z, wb[2].x, fmaf(xv.y, wb[1].x, fmaf(xv.x, wb[0].x, acc[i][0]))));
        acc[i][1] = fmaf(xv.w, wb[3].y, fmaf(xv.z, wb[2].y, fmaf(xv.y, wb[1].y, fmaf(xv.x, wb[0].y, acc[i][1]))));
        acc[i][2] = fmaf(xv.w, wb[3].z, fmaf(xv.z, wb[2].z, fmaf(xv.y, wb[1].z, fmaf(xv.x, wb[0].z, acc[i][2]))));
        acc[i][3] = fmaf(xv.w, wb[3].w, fmaf(xv.z, wb[2].w, fmaf(xv.y, wb[1].w, fmaf(xv.x, wb[0].w, acc[i][3]))));
      }
    }
  }
#pragma unroll
  for (int i = 0; i < 4; ++i) {
    float4 v; v.x = acc[i][0]; v.y = acc[i][1]; v.z = acc[i][2]; v.w = acc[i][3];
    *reinterpret_cast<float4*>(
        &part[((size_t)kc * T_TOK + r0 + rg + 32 * i) * NE + er * 4]) = v;
  }
}

// ------------- softmax + top2 + me partials (R7-proven verbatim) -------------
__global__ __launch_bounds__(64) void k_soft(const float* __restrict__ part,
                                             float2* __restrict__ g12,
                                             int* __restrict__ idxs,
                                             float* __restrict__ me_part) {
  __shared__ float lg[64][33];
  const int tid = threadIdx.x;
  const int R = blockIdx.x * 64 + tid;
  const int t = R >> 1;
  const int p = R & 1;
  float v[32];
  const float* pr = part + (size_t)t * NE + p * EE;
#pragma unroll
  for (int e = 0; e < 32; e += 4) {
    float4 s = *reinterpret_cast<const float4*>(pr + e);
    v[e] = s.x; v[e + 1] = s.y; v[e + 2] = s.z; v[e + 3] = s.w;
  }
  for (int kc = 1; kc < NKC; ++kc) {
    const float* prk = pr + (size_t)kc * T_TOK * NE;
#pragma unroll
    for (int e = 0; e < 32; e += 4) {
      float4 s = *reinterpret_cast<const float4*>(prk + e);
      v[e] += s.x; v[e + 1] += s.y; v[e + 2] += s.z; v[e + 3] += s.w;
    }
  }
  float m = v[0];
#pragma unroll
  for (int e = 1; e < 32; ++e) m = fmaxf(m, v[e]);
  float sum = 0.f;
#pragma unroll
  for (int e = 0; e < 32; ++e) { v[e] = expf(v[e] - m); sum += v[e]; }
  const float inv = 1.0f / sum;
#pragma unroll
  for (int e = 0; e < 32; ++e) v[e] *= inv;
  float g1 = -1.f; int i1 = 0;
#pragma unroll
  for (int e = 0; e < 32; ++e) if (v[e] > g1) { g1 = v[e]; i1 = e; }  // first-max
  float g2 = -1.f; int i2 = 0;
#pragma unroll
  for (int e = 0; e < 32; ++e) if (e != i1 && v[e] > g2) { g2 = v[e]; i2 = e; }
  g12[R] = make_float2(g1, g2);
  idxs[R] = i1 | (i2 << 8);
#pragma unroll
  for (int e = 0; e < 32; ++e) lg[tid][e] = v[e];
  __syncthreads();
  {
    const int pp = tid >> 5, ee = tid & 31;
    float s = 0.f;
    for (int rr = pp; rr < 64; rr += 2) s += lg[rr][ee];
    me_part[blockIdx.x * 64 + tid] = s;
  }
}

// ------- scan + inline point-fixes + l_aux (R10/R11-proven verbatim) ---------
__global__ __launch_bounds__(1024) void k_scan2(const int* __restrict__ idxs,
                                                const float2* __restrict__ g12,
                                                const float* __restrict__ me_part,
                                                int2* __restrict__ fl,
                                                float2* __restrict__ wvp,
                                                float* __restrict__ out,
                                                int rlimit) {
  __shared__ int grp[NP][64][32];
  __shared__ int tot[NP][32];
  __shared__ unsigned short tk1[NP][T_TOK];
  __shared__ unsigned short tk2[NP][T_TOK];
  __shared__ float red[64];
  const int tid = threadIdx.x;
  const int wvi = tid >> 6;
  const int p = wvi >> 3;
  const int wg = wvi & 7;
  const int l = tid & 63;
  const unsigned long long lmask = (1ull << l) - 1ull;
  for (int gi = 0; gi < 8; ++gi) {
    const int g = wg * 8 + gi;
    const int t = g * 64 + l;
    const int e1 = idxs[t * 2 + p] & 255;
    if (l < 32) grp[p][g][l] = 0;
    unsigned long long m = ~0ull;
#pragma unroll
    for (int b = 0; b < 5; ++b) {
      const unsigned long long bm = __ballot((e1 >> b) & 1);
      m &= ((e1 >> b) & 1) ? bm : ~bm;
    }
    const int rank = (int)__popcll(m & lmask);
    if (rank == 0) grp[p][g][e1] = (int)__popcll(m);
    tk1[p][t] = (unsigned short)(rank | (e1 << 6));
  }
  __syncthreads();
  if (tid < 64) {
    const int pp = tid >> 5, ee = tid & 31;
    int s = 0;
    for (int g = 0; g < 64; ++g) { int vv = grp[pp][g][ee]; grp[pp][g][ee] = s; s += vv; }
    tot[pp][ee] = s;
  }
  __syncthreads();
  for (int gi = 0; gi < 8; ++gi) {
    const int g = wg * 8 + gi;
    const int t = g * 64 + l;
    const int vv = tk1[p][t];
    tk1[p][t] = (unsigned short)(grp[p][g][vv >> 6] + (vv & 63));
  }
  if (tid < 64) {
    float s = 0.f;
    for (int b = 0; b < 128; ++b) s += me_part[b * 64 + tid];
    red[tid] = s * (float)tot[tid >> 5][tid & 31];
  }
  __syncthreads();
  if (tid == 0) {
    float s = 0.f;
    for (int i = 0; i < 64; ++i) s += red[i];
    out[0] = s / (64.0f * 4096.0f * 4096.0f);
  }
  for (int gi = 0; gi < 8; ++gi) {
    const int g = wg * 8 + gi;
    const int t = g * 64 + l;
    const int ii = idxs[t * 2 + p];
    const int e2 = (tk1[p][t] < CAP) ? (ii >> 8) : (ii & 255);
    if (l < 32) grp[p][g][l] = 0;
    unsigned long long m = ~0ull;
#pragma unroll
    for (int b = 0; b < 5; ++b) {
      const unsigned long long bm = __ballot((e2 >> b) & 1);
      m &= ((e2 >> b) & 1) ? bm : ~bm;
    }
    const int rank = (int)__popcll(m & lmask);
    if (rank == 0) grp[p][g][e2] = (int)__popcll(m);
    tk2[p][t] = (unsigned short)(rank | (e2 << 6));
  }
  __syncthreads();
  if (tid < 64) {
    const int pp = tid >> 5, ee = tid & 31;
    int s = min(tot[pp][ee], CAP);
    for (int g = 0; g < 64; ++g) { int vv = grp[pp][g][ee]; grp[pp][g][ee] = s; s += vv; }
  }
  __syncthreads();
  for (int gi = 0; gi < 8; ++gi) {
    const int g = wg * 8 + gi;
    const int t = g * 64 + l;
    const int R = t * 2 + p;
    const int ii = idxs[R];
    const int e1 = ii & 255;
    const int loc1v = tk1[p][t];
    const bool kept1 = loc1v < CAP;
    const int v2 = tk2[p][t];
    const int rank2 = v2 & 63, e2 = v2 >> 6;
    const int loc2 = grp[p][g][e2] + rank2;
    const bool kept2 = loc2 < CAP;
    const float2 gg = g12[R];
    const float gs1 = kept1 ? gg.x : 0.f;
    const float g2v = kept1 ? gg.y : gg.x;
    const float gs2 = kept2 ? g2v : 0.f;
    const float den = fmaxf(gs1 + gs2, 1.1920929e-07f);  // FLT_EPSILON
    const int f1 = kept1 ? e1 * CAP + loc1v : -1;
    const int f2 = kept2 ? e2 * CAP + loc2 : -1;
    const float w1 = gs1 / den, w2 = gs2 / den;
    fl[R] = make_int2(f1, f2);
    wvp[R] = make_float2(w1, w2);
    float* oc = out + 1 + (size_t)R * 5120;  // zeros already down
    if (f1 >= 0) oc[f1] = w1;
    if (f2 >= 0) oc[f2] = w2;
    if (R < rlimit) {
      float* od = out + 1 + COMB_ELEMS + (size_t)R * 5120;
      if (f1 >= 0) od[f1] = 1.0f;
      if (f2 >= 0) od[f2] = 1.0f;
    }
  }
}

// pathB: zero the part window (tail of dispatch) after soft consumed it
__global__ __launch_bounds__(256) void k_tailB(float* __restrict__ out) {
  float4* p4 = reinterpret_cast<float4*>(out);
  const float4 z4 = make_float4(0.f, 0.f, 0.f, 0.f);
  const int base = 20447232 + (int)blockIdx.x * 4096 + (int)threadIdx.x;
#pragma unroll
  for (int j = 0; j < 16; ++j) p4[base + j * 256] = z4;
  if (blockIdx.x == 0 && threadIdx.x == 0) out[OUT_ELEMS - 1] = 0.f;
}

// pathC: zero the part window at combine front (after soft consumed it)
__global__ __launch_bounds__(256) void k_fill2C(float* __restrict__ out) {
  float4* p4 = reinterpret_cast<float4*>(out + 4);
  const float4 z4 = make_float4(0.f, 0.f, 0.f, 0.f);
  const int base = (int)blockIdx.x * 2048 + (int)threadIdx.x;
#pragma unroll
  for (int j = 0; j < 8; ++j) p4[base + j * 256] = z4;
}

// pathC: zero dispatch-tail scratch window rows + their fixes (from fl in LDS)
__global__ __launch_bounds__(1024) void k_tailC(const int2* __restrict__ fl,
                                                float* __restrict__ out,
                                                int nfullB) {
  __shared__ int2 sfl[16];
  const int tid = threadIdx.x;
  const int rstart = nfullB * 2;
  const int nr = 8192 - rstart;  // <= 16
  if (tid < nr) sfl[tid] = fl[rstart + tid];
  __syncthreads();
  const size_t base = 1 + COMB_ELEMS + (size_t)rstart * 5120;
  const int cnt = nr * 5120;
  const int nx4 = (cnt - 4) >> 2;
  float4* p4 = (float4*)(out + base + 3);
  const float4 z4 = make_float4(0.f, 0.f, 0.f, 0.f);
  for (int idx = tid; idx < nx4; idx += 1024) p4[idx] = z4;
  if (tid < 3) out[base + tid] = 0.f;
  if (tid == 3) out[base + cnt - 1] = 0.f;
  __syncthreads();
  if (tid < 2 * nr) {
    const int rr = rstart + (tid >> 1);
    const int2 f = sfl[tid >> 1];
    const int pos = (tid & 1) ? f.y : f.x;
    if (pos >= 0) out[1 + COMB_ELEMS + (size_t)rr * 5120 + pos] = 1.0f;
  }
}

extern "C" void kernel_launch(void* const* d_in, const int* in_sizes, int n_in,
                              void* d_out, int out_size, void* d_ws, size_t ws_size,
                              hipStream_t stream) {
  const float* x = (const float*)d_in[0];
  const float* W = (const float*)d_in[1];
  float* out = (float*)d_out;

  const bool pathA = ws_size >= (SMALLF + PARTF) * sizeof(float);
  const bool pathB = !pathA && ws_size >= SMALLF * sizeof(float);

  float* small;
  float* part;
  int s1lo = 0, s1hi = 0, s2lo = 0, s2hi = 0, fillLast = 1;
  int rlimit = 8192, nfullB = 4096;
  if (pathA) {
    small = (float*)d_ws;
    part = small + SMALLF;
  } else if (pathB) {
    small = (float*)d_ws;
    part = out + PB_F;
    s1lo = PB_F / 4; s1hi = TOT4;
    fillLast = 0;
  } else {
    const size_t tb = (OUT_ELEMS - SMALLF) & ~(size_t)3;  // 83820544
    small = out + tb;
    part = out + 4;
    s1lo = 1; s1hi = 1 + (int)(PARTF / 4);
    s2lo = (int)(tb / 4); s2hi = TOT4;
    fillLast = 0;
    nfullB = (int)((tb - 1 - COMB_ELEMS) / 10240);  // 4089
    rlimit = nfullB * 2;
  }
  float2* g12 = (float2*)small;
  int* idxs = (int*)(small + 16384);
  float* me_part = small + 24576;
  int2* fl = (int2*)(small + 32768);
  float2* wvp = (float2*)(small + 49152);

  hipLaunchKernelGGL(k_fused, dim3(2304), dim3(512), 0, stream,
                     x, W, part, out, s1lo, s1hi, s2lo, s2hi, fillLast);
  hipLaunchKernelGGL(k_soft, dim3(128), dim3(64), 0, stream, part, g12, idxs, me_part);
  if (pathB)
    hipLaunchKernelGGL(k_tailB, dim3(128), dim3(256), 0, stream, out);
  if (!pathA && !pathB)
    hipLaunchKernelGGL(k_fill2C, dim3(256), dim3(256), 0, stream, out);
  hipLaunchKernelGGL(k_scan2, dim3(1), dim3(1024), 0, stream,
                     idxs, g12, me_part, fl, wvp, out, rlimit);
  if (!pathA && !pathB)
    hipLaunchKernelGGL(k_tailC, dim3(1), dim3(1024), 0, stream, fl, out, nfullB);
}

// Round 16
// 108.648 us; speedup vs baseline: 3.2593x; 1.0552x over previous
//
#include <hip/hip_runtime.h>
#include <cstdint>

#define T_TOK 4096
#define KDIM 2048
#define NE 64
#define NP 2
#define EE 32
#define CAP 160
#define NKC 8
#define KCHUNK 256
#define BLKR 128
#define COMB_ELEMS 41943040ull /* 8192 * 5120 */
#define OUT_ELEMS 83886081ull  /* 1 + 2*COMB */
#define PARTF 2097152ull
#define TOT4 20971520
#define SMALLF 65536           /* g12 16384 | idxs 8192 | me 8192 | fl 16384 | wvp 16384 */
#define PB_F 81788928          /* pathB part offset (16B-aligned float idx) */
#define NFA 3300               /* fill spans in fused  (264 MB) */
#define NFB 450                /* fill spans in soft   (36 MB)  */
#define NFC 346                /* fill spans in scan   (27.7 MB); NFA+NFB+NFC=4096 */

template <int NTH, int ITERS>
__device__ __forceinline__ void fill_span(float* __restrict__ out, int span, int tid,
                                          int s1lo, int s1hi, int s2lo, int s2hi,
                                          int fillLast) {
  float4* p4 = reinterpret_cast<float4*>(out);
  const float4 z4 = make_float4(0.f, 0.f, 0.f, 0.f);
  const int start = span * 5120;
#pragma unroll
  for (int j = 0; j < ITERS; ++j) {
    const int i4 = start + tid + j * NTH;
    if (i4 >= s1lo && i4 < s1hi) continue;
    if (i4 >= s2lo && i4 < s2hi) continue;
    p4[i4] = z4;
  }
  if (fillLast && span == 4095 && tid == NTH - 1) out[OUT_ELEMS - 1] = 0.f;
}

// ---- fused: blocks 0..255 = gemm (R6-proven 256t, 8r x 4e); rest = fill -----
__global__ __launch_bounds__(256)
void k_fused(const float* __restrict__ x, const float* __restrict__ W,
             float* __restrict__ part, float* __restrict__ out,
             int s1lo, int s1hi, int s2lo, int s2hi) {
  __shared__ float xs[BLKR][36];
  __shared__ float wt[32][68];
  const int tid = threadIdx.x;
  if (blockIdx.x >= 256) {
    fill_span<256, 20>(out, (int)blockIdx.x - 256, tid, s1lo, s1hi, s2lo, s2hi, 0);
    return;
  }
  const int rb = (int)blockIdx.x & 31;
  const int kc = (int)blockIdx.x >> 5;
  const int r0 = rb * BLKR;
  const int er = tid & 15;
  const int rg = tid >> 4;
  float acc[8][4];
#pragma unroll
  for (int i = 0; i < 8; ++i)
#pragma unroll
    for (int c = 0; c < 4; ++c) acc[i][c] = 0.f;
  float4 sx[4], sw[2];
  {
    const int kb = kc * KCHUNK;
#pragma unroll
    for (int q = 0; q < 4; ++q) {
      const int li = tid + q * 256, row = li >> 3, kq = (li & 7) * 4;
      sx[q] = *reinterpret_cast<const float4*>(&x[(size_t)(r0 + row) * KDIM + kb + kq]);
    }
#pragma unroll
    for (int q = 0; q < 2; ++q) {
      const int li = tid + q * 256, e = li >> 3, kq = (li & 7) * 4;
      sw[q] = *reinterpret_cast<const float4*>(&W[(size_t)e * KDIM + kb + kq]);
    }
  }
  for (int s = 0; s < 8; ++s) {
    __syncthreads();
#pragma unroll
    for (int q = 0; q < 4; ++q) {
      const int li = tid + q * 256, row = li >> 3, kq = (li & 7) * 4;
      *reinterpret_cast<float4*>(&xs[row][kq]) = sx[q];
    }
#pragma unroll
    for (int q = 0; q < 2; ++q) {
      const int li = tid + q * 256, e = li >> 3, kq = (li & 7) * 4;
      wt[kq][e] = sw[q].x; wt[kq + 1][e] = sw[q].y;
      wt[kq + 2][e] = sw[q].z; wt[kq + 3][e] = sw[q].w;
    }
    if (s < 7) {
      const int kb = kc * KCHUNK + (s + 1) * 32;
#pragma unroll
      for (int q = 0; q < 4; ++q) {
        const int li = tid + q * 256, row = li >> 3, kq = (li & 7) * 4;
        sx[q] = *reinterpret_cast<const float4*>(&x[(size_t)(r0 + row) * KDIM + kb + kq]);
      }
#pragma unroll
      for (int q = 0; q < 2; ++q) {
        const int li = tid + q * 256, e = li >> 3, kq = (li & 7) * 4;
        sw[q] = *reinterpret_cast<const float4*>(&W[(size_t)e * KDIM + kb + kq]);
      }
    }
    __syncthreads();
#pragma unroll
    for (int k4 = 0; k4 < 8; ++k4) {
      float4 wb[4];
#pragma unroll
      for (int j = 0; j < 4; ++j)
        wb[j] = *reinterpret_cast<const float4*>(&wt[k4 * 4 + j][er * 4]);
#pragma unroll
      for (int i = 0; i < 8; ++i) {
        const float4 xv = *reinterpret_cast<const float4*>(&xs[rg + 16 * i][k4 * 4]);
        acc[i][0] = fmaf(xv.w, wb[3].x, fmaf(xv.z, wb[2].x, fmaf(xv.y, wb[1].x, fmaf(xv.x, wb[0].x, acc[i][0]))));
        acc[i][1] = fmaf(xv.w, wb[3].y, fmaf(xv.z, wb[2].y, fmaf(xv.y, wb[1].y, fmaf(xv.x, wb[0].y, acc[i][1]))));
        acc[i][2] = fmaf(xv.w, wb[3].z, fmaf(xv.z, wb[2].z, fmaf(xv.y, wb[1].z, fmaf(xv.x, wb[0].z, acc[i][2]))));
        acc[i][3] = fmaf(xv.w, wb[3].w, fmaf(xv.z, wb[2].w, fmaf(xv.y, wb[1].w, fmaf(xv.x, wb[0].w, acc[i][3]))));
      }
    }
  }
#pragma unroll
  for (int i = 0; i < 8; ++i) {
    float4 v; v.x = acc[i][0]; v.y = acc[i][1]; v.z = acc[i][2]; v.w = acc[i][3];
    *reinterpret_cast<float4*>(
        &part[((size_t)kc * T_TOK + r0 + rg + 16 * i) * NE + er * 4]) = v;
  }
}

// ---- soft2: blocks 0..31 = softmax (wave w == original 64t block, bitwise);
// ---- blocks 32.. = fill spans NFA.. ----------------------------------------
__global__ __launch_bounds__(256)
void k_soft2(const float* __restrict__ part, float2* __restrict__ g12,
             int* __restrict__ idxs, float* __restrict__ me_part,
             float* __restrict__ out,
             int s1lo, int s1hi, int s2lo, int s2hi) {
  __shared__ float lg[256][33];
  const int tid = threadIdx.x;
  if (blockIdx.x >= 32) {
    fill_span<256, 20>(out, NFA + (int)blockIdx.x - 32, tid, s1lo, s1hi, s2lo, s2hi, 0);
    return;
  }
  const int R = (int)blockIdx.x * 256 + tid;  // == ob*64 + tid64
  const int t = R >> 1;
  const int p = R & 1;
  float v[32];
  const float* pr = part + (size_t)t * NE + p * EE;
#pragma unroll
  for (int e = 0; e < 32; e += 4) {
    float4 s = *reinterpret_cast<const float4*>(pr + e);
    v[e] = s.x; v[e + 1] = s.y; v[e + 2] = s.z; v[e + 3] = s.w;
  }
  for (int kc = 1; kc < NKC; ++kc) {
    const float* prk = pr + (size_t)kc * T_TOK * NE;
#pragma unroll
    for (int e = 0; e < 32; e += 4) {
      float4 s = *reinterpret_cast<const float4*>(prk + e);
      v[e] += s.x; v[e + 1] += s.y; v[e + 2] += s.z; v[e + 3] += s.w;
    }
  }
  float m = v[0];
#pragma unroll
  for (int e = 1; e < 32; ++e) m = fmaxf(m, v[e]);
  float sum = 0.f;
#pragma unroll
  for (int e = 0; e < 32; ++e) { v[e] = expf(v[e] - m); sum += v[e]; }
  const float inv = 1.0f / sum;
#pragma unroll
  for (int e = 0; e < 32; ++e) v[e] *= inv;
  float g1 = -1.f; int i1 = 0;
#pragma unroll
  for (int e = 0; e < 32; ++e) if (v[e] > g1) { g1 = v[e]; i1 = e; }  // first-max
  float g2 = -1.f; int i2 = 0;
#pragma unroll
  for (int e = 0; e < 32; ++e) if (e != i1 && v[e] > g2) { g2 = v[e]; i2 = e; }
  g12[R] = make_float2(g1, g2);
  idxs[R] = i1 | (i2 << 8);
#pragma unroll
  for (int e = 0; e < 32; ++e) lg[tid][e] = v[e];
  __syncthreads();
  {  // wave-local me partial, bitwise == original 128x64 layout
    const int wbase = (tid >> 6) * 64;
    const int pp = (tid & 63) >> 5, ee = tid & 31;
    float s = 0.f;
    for (int rr = pp; rr < 64; rr += 2) s += lg[wbase + rr][ee];
    me_part[(int)blockIdx.x * 256 + tid] = s;
  }
}

// ---- scanf: block 0 = ordered scans (results to scratch + out[0]);
// ---- blocks 1.. = fill spans NFA+NFB.. --------------------------------------
__global__ __launch_bounds__(1024)
void k_scanf(const int* __restrict__ idxs, const float2* __restrict__ g12,
             const float* __restrict__ me_part, int2* __restrict__ fl,
             float2* __restrict__ wvp, float* __restrict__ out,
             int s1lo, int s1hi, int s2lo, int s2hi, int fillLast) {
  const int tid = threadIdx.x;
  if (blockIdx.x >= 1) {
    fill_span<1024, 5>(out, NFA + NFB + (int)blockIdx.x - 1, tid,
                       s1lo, s1hi, s2lo, s2hi, fillLast);
    return;
  }
  __shared__ int grp[NP][64][32];
  __shared__ int tot[NP][32];
  __shared__ unsigned short tk1[NP][T_TOK];
  __shared__ unsigned short tk2[NP][T_TOK];
  __shared__ float red[64];
  const int wvi = tid >> 6;
  const int p = wvi >> 3;
  const int wg = wvi & 7;
  const int l = tid & 63;
  const unsigned long long lmask = (1ull << l) - 1ull;
  for (int gi = 0; gi < 8; ++gi) {
    const int g = wg * 8 + gi;
    const int t = g * 64 + l;
    const int e1 = idxs[t * 2 + p] & 255;
    if (l < 32) grp[p][g][l] = 0;
    unsigned long long m = ~0ull;
#pragma unroll
    for (int b = 0; b < 5; ++b) {
      const unsigned long long bm = __ballot((e1 >> b) & 1);
      m &= ((e1 >> b) & 1) ? bm : ~bm;
    }
    const int rank = (int)__popcll(m & lmask);
    if (rank == 0) grp[p][g][e1] = (int)__popcll(m);
    tk1[p][t] = (unsigned short)(rank | (e1 << 6));
  }
  __syncthreads();
  if (tid < 64) {
    const int pp = tid >> 5, ee = tid & 31;
    int s = 0;
    for (int g = 0; g < 64; ++g) { int vv = grp[pp][g][ee]; grp[pp][g][ee] = s; s += vv; }
    tot[pp][ee] = s;
  }
  __syncthreads();
  for (int gi = 0; gi < 8; ++gi) {
    const int g = wg * 8 + gi;
    const int t = g * 64 + l;
    const int vv = tk1[p][t];
    tk1[p][t] = (unsigned short)(grp[p][g][vv >> 6] + (vv & 63));
  }
  if (tid < 64) {
    float s = 0.f;
    for (int b = 0; b < 128; ++b) s += me_part[b * 64 + tid];
    red[tid] = s * (float)tot[tid >> 5][tid & 31];
  }
  __syncthreads();
  if (tid == 0) {
    float s = 0.f;
    for (int i = 0; i < 64; ++i) s += red[i];
    out[0] = s / (64.0f * 4096.0f * 4096.0f);
  }
  for (int gi = 0; gi < 8; ++gi) {
    const int g = wg * 8 + gi;
    const int t = g * 64 + l;
    const int ii = idxs[t * 2 + p];
    const int e2 = (tk1[p][t] < CAP) ? (ii >> 8) : (ii & 255);
    if (l < 32) grp[p][g][l] = 0;
    unsigned long long m = ~0ull;
#pragma unroll
    for (int b = 0; b < 5; ++b) {
      const unsigned long long bm = __ballot((e2 >> b) & 1);
      m &= ((e2 >> b) & 1) ? bm : ~bm;
    }
    const int rank = (int)__popcll(m & lmask);
    if (rank == 0) grp[p][g][e2] = (int)__popcll(m);
    tk2[p][t] = (unsigned short)(rank | (e2 << 6));
  }
  __syncthreads();
  if (tid < 64) {
    const int pp = tid >> 5, ee = tid & 31;
    int s = min(tot[pp][ee], CAP);
    for (int g = 0; g < 64; ++g) { int vv = grp[pp][g][ee]; grp[pp][g][ee] = s; s += vv; }
  }
  __syncthreads();
  for (int gi = 0; gi < 8; ++gi) {
    const int g = wg * 8 + gi;
    const int t = g * 64 + l;
    const int R = t * 2 + p;
    const int ii = idxs[R];
    const int e1 = ii & 255;
    const int loc1v = tk1[p][t];
    const bool kept1 = loc1v < CAP;
    const int v2 = tk2[p][t];
    const int rank2 = v2 & 63, e2 = v2 >> 6;
    const int loc2 = grp[p][g][e2] + rank2;
    const bool kept2 = loc2 < CAP;
    const float2 gg = g12[R];
    const float gs1 = kept1 ? gg.x : 0.f;
    const float g2v = kept1 ? gg.y : gg.x;
    const float gs2 = kept2 ? g2v : 0.f;
    const float den = fmaxf(gs1 + gs2, 1.1920929e-07f);  // FLT_EPSILON
    fl[R] = make_int2(kept1 ? e1 * CAP + loc1v : -1, kept2 ? e2 * CAP + loc2 : -1);
    wvp[R] = make_float2(gs1 / den, gs2 / den);
  }
}

// ---- fix: <=4 point stores per row into fully-zeroed output -----------------
__global__ __launch_bounds__(256) void k_fix(const int2* __restrict__ fl,
                                             const float2* __restrict__ wvp,
                                             float* __restrict__ out,
                                             int rlimit) {
  const int R = (int)blockIdx.x * 256 + threadIdx.x;
  const int2 f = fl[R];
  const float2 w = wvp[R];
  float* oc = out + 1 + (size_t)R * 5120;
  if (f.x >= 0) oc[f.x] = w.x;
  if (f.y >= 0) oc[f.y] = w.y;
  if (R < rlimit) {
    float* od = out + 1 + COMB_ELEMS + (size_t)R * 5120;
    if (f.x >= 0) od[f.x] = 1.0f;
    if (f.y >= 0) od[f.y] = 1.0f;
  }
}

// pathB: zero the part window (tail of dispatch) after soft consumed it
__global__ __launch_bounds__(256) void k_tailB(float* __restrict__ out) {
  float4* p4 = reinterpret_cast<float4*>(out);
  const float4 z4 = make_float4(0.f, 0.f, 0.f, 0.f);
  const int base = 20447232 + (int)blockIdx.x * 4096 + (int)threadIdx.x;
#pragma unroll
  for (int j = 0; j < 16; ++j) p4[base + j * 256] = z4;
  if (blockIdx.x == 0 && threadIdx.x == 0) out[OUT_ELEMS - 1] = 0.f;
}

// pathC: zero the part window at combine front (after soft consumed it)
__global__ __launch_bounds__(256) void k_fill2C(float* __restrict__ out) {
  float4* p4 = reinterpret_cast<float4*>(out + 4);
  const float4 z4 = make_float4(0.f, 0.f, 0.f, 0.f);
  const int base = (int)blockIdx.x * 2048 + (int)threadIdx.x;
#pragma unroll
  for (int j = 0; j < 8; ++j) p4[base + j * 256] = z4;
}

// pathC: zero dispatch-tail scratch window rows + their fixes (fl staged first)
__global__ __launch_bounds__(1024) void k_tailC(const int2* __restrict__ fl,
                                                float* __restrict__ out,
                                                int rstart) {
  __shared__ int2 sfl[16];
  const int tid = threadIdx.x;
  const int nr = 8192 - rstart;  // <= 16
  if (tid < nr) sfl[tid] = fl[rstart + tid];
  __syncthreads();
  const size_t base = 1 + COMB_ELEMS + (size_t)rstart * 5120;
  const int cnt = nr * 5120;
  const int nx4 = (cnt - 4) >> 2;
  float4* p4 = (float4*)(out + base + 3);
  const float4 z4 = make_float4(0.f, 0.f, 0.f, 0.f);
  for (int idx = tid; idx < nx4; idx += 1024) p4[idx] = z4;
  if (tid < 3) out[base + tid] = 0.f;
  if (tid == 3) out[base + cnt - 1] = 0.f;
  __syncthreads();
  if (tid < 2 * nr) {
    const int rr = rstart + (tid >> 1);
    const int2 f = sfl[tid >> 1];
    const int pos = (tid & 1) ? f.y : f.x;
    if (pos >= 0) out[1 + COMB_ELEMS + (size_t)rr * 5120 + pos] = 1.0f;
  }
}

extern "C" void kernel_launch(void* const* d_in, const int* in_sizes, int n_in,
                              void* d_out, int out_size, void* d_ws, size_t ws_size,
                              hipStream_t stream) {
  const float* x = (const float*)d_in[0];
  const float* W = (const float*)d_in[1];
  float* out = (float*)d_out;

  const bool pathA = ws_size >= (SMALLF + PARTF) * sizeof(float);
  const bool pathB = !pathA && ws_size >= SMALLF * sizeof(float);

  float* small;
  float* part;
  int s1lo = 0, s1hi = 0, s2lo = 0, s2hi = 0, fillLast = 1;
  int rlimit = 8192, rstart = 8192;
  if (pathA) {
    small = (float*)d_ws;
    part = small + SMALLF;
  } else if (pathB) {
    small = (float*)d_ws;
    part = out + PB_F;
    s1lo = PB_F / 4; s1hi = TOT4;
    fillLast = 0;  // tailB writes last elem
  } else {
    const size_t tb = (OUT_ELEMS - SMALLF) & ~(size_t)3;  // 83820544
    small = out + tb;
    part = out + 4;
    s1lo = 1; s1hi = 1 + (int)(PARTF / 4);
    s2lo = (int)(tb / 4); s2hi = TOT4;
    fillLast = 0;  // tailC writes last elem
    rstart = (int)((tb - 1 - COMB_ELEMS) / 5120);  // 8179 (first overlapping row)
    rlimit = rstart;
  }
  float2* g12 = (float2*)small;
  int* idxs = (int*)(small + 16384);
  float* me_part = small + 24576;
  int2* fl = (int2*)(small + 32768);
  float2* wvp = (float2*)(small + 49152);

  hipLaunchKernelGGL(k_fused, dim3(256 + NFA), dim3(256), 0, stream,
                     x, W, part, out, s1lo, s1hi, s2lo, s2hi);
  hipLaunchKernelGGL(k_soft2, dim3(32 + NFB), dim3(256), 0, stream,
                     part, g12, idxs, me_part, out, s1lo, s1hi, s2lo, s2hi);
  if (pathB)
    hipLaunchKernelGGL(k_tailB, dim3(128), dim3(256), 0, stream, out);
  if (!pathA && !pathB)
    hipLaunchKernelGGL(k_fill2C, dim3(256), dim3(256), 0, stream, out);
  hipLaunchKernelGGL(k_scanf, dim3(1 + NFC), dim3(1024), 0, stream,
                     idxs, g12, me_part, fl, wvp, out, s1lo, s1hi, s2lo, s2hi, fillLast);
  hipLaunchKernelGGL(k_fix, dim3(32), dim3(256), 0, stream, fl, wvp, out, rlimit);
  if (!pathA && !pathB)
    hipLaunchKernelGGL(k_tailC, dim3(1), dim3(1024), 0, stream, fl, out, rstart);
}